// Round 9
// baseline (517.975 us; speedup 1.0000x reference)
//
#include <hip/hip_runtime.h>
#include <math.h>

#define EPSF 1e-5f
#define GAPTH 1e-3f
#define NKS 3           // K-split slices for logits GEMM
#define RROWS 18432

// B=128, C=8, H=144, W=144, CW=1152, R=18432, TW=5, OG=2, NCLS=6, DT=256, ITC=5760
// Collapsed head: logits[row, j] = sum_k Wc[j,k] * x'[row,k] + cconst[j]
//   j 0..143 = cls, j 144..145 = ext, j 146..159 = zero pad. NP=160.

typedef __attribute__((ext_vector_type(8))) short short8v;
typedef __attribute__((ext_vector_type(4))) float f32x4;
typedef unsigned short ushort;
typedef unsigned int uint;

__device__ inline ushort f2bf(float f) {
    uint u = __float_as_uint(f);
    uint r = (u + 0x7FFFu + ((u >> 16) & 1u)) >> 16;
    return (ushort)r;
}
__device__ inline float bf2f(ushort h) { return __uint_as_float(((uint)h) << 16); }

// ---------------------------------------------------------------------------
// Build combined weights: Wc[j,k] = sum_o w2[j,o]*s[o]*w1[o,k], s = g*rsqrt(v+eps)
// cconst[j] = sum_o w2[j,o]*((b1[o]-m[o])*s[o]+bb[o]) + b2[j].  Also bf16 hi/lo.
// ---------------------------------------------------------------------------
__global__ __launch_bounds__(256) void wcomb_build(
    const float* __restrict__ w1e, const float* __restrict__ b1e, const float* __restrict__ ge,
    const float* __restrict__ bbe, const float* __restrict__ me, const float* __restrict__ ve,
    const float* __restrict__ w2e, const float* __restrict__ b2e,
    const float* __restrict__ w1c, const float* __restrict__ b1c, const float* __restrict__ gc,
    const float* __restrict__ bbc, const float* __restrict__ mc, const float* __restrict__ vc,
    const float* __restrict__ w2c, const float* __restrict__ b2c,
    float* __restrict__ Wc32, ushort* __restrict__ Wchi, ushort* __restrict__ Wclo,
    float* __restrict__ cconst)
{
    __shared__ float coef[256];
    __shared__ float csum[4];
    const int j = blockIdx.x, tid = threadIdx.x;
    const int lane = tid & 63, wid = tid >> 6;

    const float *w1 = nullptr, *w2row = nullptr, *b1 = nullptr, *g = nullptr,
                *bb = nullptr, *m = nullptr, *v = nullptr;
    float b2v = 0.f;
    int valid = 0;
    if (j < 144) {
        valid = 1; w1 = w1c; w2row = w2c + (size_t)j * 256;
        b1 = b1c; g = gc; bb = bbc; m = mc; v = vc; b2v = b2c[j];
    } else if (j < 146) {
        valid = 1; w1 = w1e; w2row = w2e + (size_t)(j - 144) * 256;
        b1 = b1e; g = ge; bb = bbe; m = me; v = ve; b2v = b2e[j - 144];
    }

    float cf = 0.f, cc = 0.f;
    if (valid) {
        float s = g[tid] * rsqrtf(v[tid] + EPSF);
        float w2v = w2row[tid];
        cf = w2v * s;
        cc = w2v * ((b1[tid] - m[tid]) * s + bb[tid]);
    }
    coef[tid] = cf;
    float t = cc;
#pragma unroll
    for (int off = 32; off; off >>= 1) t += __shfl_xor(t, off);
    if (lane == 0) csum[wid] = t;
    __syncthreads();
    if (tid == 0) cconst[j] = valid ? ((csum[0] + csum[1]) + (csum[2] + csum[3]) + b2v) : 0.f;

    for (int k = tid; k < 1152; k += 256) {
        float acc = 0.f;
        if (valid) {
            for (int o = 0; o < 256; o++) acc += coef[o] * w1[(size_t)o * 1152 + k];
        }
        Wc32[(size_t)j * 1152 + k] = acc;
        ushort hi = f2bf(acc);
        Wchi[(size_t)j * 1152 + k] = hi;
        Wclo[(size_t)j * 1152 + k] = f2bf(acc - bf2f(hi));
    }
}

__global__ void zero_counters(int* __restrict__ cand_count)
{
    *cand_count = 0;
}

// ---------------------------------------------------------------------------
// tiled transpose: src[R][Cc] -> dst[Cc][R]
// ---------------------------------------------------------------------------
__global__ __launch_bounds__(256) void transpose_w(
    const float* __restrict__ src, float* __restrict__ dst, int R, int Cc)
{
    __shared__ float tile[32][33];
    const int rb = blockIdx.y * 32, cb = blockIdx.x * 32;
    const int tx = threadIdx.x & 31, ty = threadIdx.x >> 5;   // ty 0..7
#pragma unroll
    for (int i = ty; i < 32; i += 8) {
        int r = rb + i, c = cb + tx;
        tile[i][tx] = (r < R && c < Cc) ? src[(size_t)r * Cc + c] : 0.f;
    }
    __syncthreads();
#pragma unroll
    for (int i = ty; i < 32; i += 8) {
        int c = cb + i, r = rb + tx;
        if (c < Cc && r < R) dst[(size_t)c * R + r] = tile[tx][i];
    }
}

// ---------------------------------------------------------------------------
// logits GEMM: M=18432, N=160(146 used), K=1152 split into NKS slices of 384.
// NO LDS, NO barriers: MFMA fragments loaded directly to registers.
//   A: lane reads 8 contiguous k-floats of its x-row, converts to bf16 hi/lo.
//   B: lane reads its 16B fragment of Wchi/Wclo straight from L2.
// Split-bf16 MFMA (hi/lo, 3 products) -> bit-identical logits vs LDS version.
// BM=32, BN=160; 4 waves as 2m x 2n; wave tile 16x80 (5 16x16 frags).
// PATCH=1: x columns in argmax window replaced by refined5 (predicated on *flag)
// ---------------------------------------------------------------------------
template<int PATCH>
__global__ __launch_bounds__(256) void logits_gemm(
    const float* __restrict__ x, const ushort* __restrict__ Wchi, const ushort* __restrict__ Wclo,
    const int* __restrict__ amax,
    const float* __restrict__ refined5, const int* __restrict__ flag,
    float* __restrict__ logits_part)
{
    const int tid = threadIdx.x;
    const int lane = tid & 63, wid = tid >> 6;
    const int wm = wid & 1, wn = wid >> 1;
    const int rb = blockIdx.x * 32;
    const int ks = blockIdx.y;
    const int kbase = ks * (1152 / NKS);        // 384 per slice
    const int NIT = (1152 / NKS) / 32;          // 12

    const int fr = lane & 15, fg = (lane >> 4) << 3;
    const int arow = rb + wm * 16 + fr;
    const int ab = arow / 144, ahh = arow - ab * 144;
    int fl = 0, pa = 0;
    if (PATCH) { fl = *flag; if (fl) pa = amax[arow]; }

    const size_t xbase = (size_t)ab * 165888 + (size_t)ahh * 144;  // + c*20736 + w

    f32x4 acc[5];
#pragma unroll
    for (int nt = 0; nt < 5; nt++) acc[nt] = (f32x4){0.f, 0.f, 0.f, 0.f};

    for (int t = 0; t < NIT; t++) {
        const int k0 = kbase + t * 32 + fg;          // multiple of 8
        const int c = k0 / 144, w = k0 - c * 144;    // w in {0,8,...,136}; 8 floats same c
        const float* xp = x + xbase + (size_t)c * 20736 + w;
        const float4 a0 = *reinterpret_cast<const float4*>(xp);
        const float4 a1 = *reinterpret_cast<const float4*>(xp + 4);
        float av[8] = {a0.x, a0.y, a0.z, a0.w, a1.x, a1.y, a1.z, a1.w};
        if (PATCH && fl) {
            const int d0 = w - pa + 2;
            const int rbase = ab * 5760 + (c * 144 + ahh) * 5;
#pragma unroll
            for (int q = 0; q < 8; q++) {
                int dw = d0 + q;
                if (dw >= 0 && dw < 5) av[q] = refined5[rbase + dw];
            }
        }
        short8v ah, al;
#pragma unroll
        for (int q = 0; q < 8; q++) {
            ushort h = f2bf(av[q]);
            ah[q] = (short)h;
            al[q] = (short)f2bf(av[q] - bf2f(h));
        }
        const size_t bko = (size_t)k0;
#pragma unroll
        for (int nt = 0; nt < 5; nt++) {
            const size_t boff = (size_t)(wn * 80 + nt * 16 + fr) * 1152 + bko;
            short8v bh = *reinterpret_cast<const short8v*>(Wchi + boff);
            short8v bl = *reinterpret_cast<const short8v*>(Wclo + boff);
            acc[nt] = __builtin_amdgcn_mfma_f32_16x16x32_bf16(ah, bh, acc[nt], 0, 0, 0);
            acc[nt] = __builtin_amdgcn_mfma_f32_16x16x32_bf16(ah, bl, acc[nt], 0, 0, 0);
            acc[nt] = __builtin_amdgcn_mfma_f32_16x16x32_bf16(al, bh, acc[nt], 0, 0, 0);
        }
    }

    // epilogue: C/D layout col=lane&15, row=(lane>>4)*4+i  [m89-verified]
    float* base = logits_part + (size_t)ks * RROWS * 160;
    const int orow = rb + wm * 16 + ((lane >> 4) << 2);
#pragma unroll
    for (int nt = 0; nt < 5; nt++) {
        int gcol = wn * 80 + nt * 16 + fr;
        if (gcol < 146) {
            float* dst = base + (size_t)orow * 160 + gcol;
#pragma unroll
            for (int i = 0; i < 4; i++)
                dst[(size_t)i * 160] = acc[nt][i];
        }
    }
}

// ---------------------------------------------------------------------------
// merged softmax over summed K-slices: cls cols 0..143 (+argmax & gap->cands),
// ext cols 144..145.  One wave per row, 4 rows per block.
// ---------------------------------------------------------------------------
__global__ __launch_bounds__(256) void softmax_heads(
    const float* __restrict__ logits_part, const float* __restrict__ cconst,
    float* __restrict__ out_cls, float* __restrict__ out_ext,
    int* __restrict__ amax, float* __restrict__ partials,
    int* __restrict__ cand_count, int* __restrict__ cand_list)
{
    __shared__ float ps[4];
    int row = blockIdx.x * 4 + (threadIdx.x >> 6);
    int lane = threadIdx.x & 63;
    const float* L0 = logits_part + (size_t)row * 160;
    const float* L1 = L0 + (size_t)RROWS * 160;
    const float* L2 = L1 + (size_t)RROWS * 160;
    float v0 = L0[lane] + L1[lane] + L2[lane] + cconst[lane];
    float v1 = L0[lane + 64] + L1[lane + 64] + L2[lane + 64] + cconst[lane + 64];
    float v2 = (lane < 16) ? (L0[lane + 128] + L1[lane + 128] + L2[lane + 128] + cconst[lane + 128])
                           : -3.0e38f;
    // argmax (first-max tie rule) + top-2 values
    float m = v0; int mi = lane;
    if (v1 > m) { m = v1; mi = lane + 64; }
    if (v2 > m) { m = v2; mi = lane + 128; }
    float m1 = v0, m2 = -3.0e38f;
    if (v1 > m1) { m2 = m1; m1 = v1; } else m2 = v1;
    if (v2 > m1) { m2 = m1; m1 = v2; } else m2 = fmaxf(m2, v2);
#pragma unroll
    for (int off = 32; off; off >>= 1) {
        float om = __shfl_xor(m, off);
        int   oi = __shfl_xor(mi, off);
        if (om > m || (om == m && oi < mi)) { m = om; mi = oi; }
        float om1 = __shfl_xor(m1, off);
        float om2 = __shfl_xor(m2, off);
        float nm1 = fmaxf(m1, om1);
        m2 = fmaxf(fminf(m1, om1), fmaxf(m2, om2));
        m1 = nm1;
    }
    float e0 = expf(v0 - m), e1 = expf(v1 - m);
    float e2 = (lane < 16) ? expf(v2 - m) : 0.f;
    float s = e0 + e1 + e2;
#pragma unroll
    for (int off = 32; off; off >>= 1) s += __shfl_xor(s, off);
    float inv = 1.f / s;
    float* O = out_cls + (size_t)row * 144;
    O[lane] = e0 * inv;
    O[lane + 64] = e1 * inv;
    if (lane < 16) O[lane + 128] = e2 * inv;

    // ext head (2 logits)
    float l0 = L0[144] + L1[144] + L2[144] + cconst[144];
    float l1 = L0[145] + L1[145] + L2[145] + cconst[145];
    float mx = fmaxf(l0, l1);
    float ee0 = expf(l0 - mx), ee1 = expf(l1 - mx);
    float einv = 1.f / (ee0 + ee1);
    float p0 = ee0 * einv;
    if (lane == 0) {
        out_ext[(size_t)row * 2] = p0;
        out_ext[(size_t)row * 2 + 1] = ee1 * einv;
        if (amax != nullptr) {
            amax[row] = mi;
            if (m1 - m2 < GAPTH) {
                int slot = atomicAdd(cand_count, 1);
                cand_list[slot] = row;
            }
        }
    }
    if (partials != nullptr) {
        if (lane == 0) ps[threadIdx.x >> 6] = p0;
        __syncthreads();
        if (threadIdx.x == 0) partials[blockIdx.x] = (ps[0] + ps[1]) + (ps[2] + ps[3]);
    }
}

__global__ __launch_bounds__(256) void reduce_flag(const float* __restrict__ partials, int n,
                                                   int* __restrict__ flag)
{
    __shared__ float sm[256];
    int tid = threadIdx.x;
    float s = 0.f;
    for (int i = tid; i < n; i += 256) s += partials[i];
    sm[tid] = s; __syncthreads();
    for (int off = 128; off; off >>= 1) {
        if (tid < off) sm[tid] += sm[tid + off];
        __syncthreads();
    }
    if (tid == 0) *flag = (sm[0] * (1.f / 18432.f) > 0.3f) ? 1 : 0;
}

// ---------------------------------------------------------------------------
// fixup over compacted candidate list: exact f32 two-stage recompute of argmax.
// Transposed weights -> per-k coalesced loads, thread-parallel dots.
// ---------------------------------------------------------------------------
__global__ __launch_bounds__(256) void fixup_list(
    const int* __restrict__ cand_count, const int* __restrict__ cand_list,
    const float* __restrict__ x,
    const float* __restrict__ w1cT, const float* __restrict__ b1c,
    const float* __restrict__ gc, const float* __restrict__ bbc,
    const float* __restrict__ mc, const float* __restrict__ vc,
    const float* __restrict__ w2cT, const float* __restrict__ b2c,
    int* __restrict__ amax)
{
    __shared__ float xrow[1152];
    __shared__ float hsh[256];
    __shared__ float Lsh[144];
    const int tid = threadIdx.x;
    const int n = *cand_count;

    for (int ci = blockIdx.x; ci < n; ci += gridDim.x) {
        const int row = cand_list[ci];
        const int b = row / 144, hh = row - b * 144;
        for (int e = tid; e < 1152; e += 256) {
            int c = e / 144, w = e - c * 144;
            xrow[e] = x[(((size_t)(b * 8 + c) * 144 + hh) * 144) + w];
        }
        __syncthreads();
        // stage 1: thread tid owns output o=tid; w1cT[k][o] coalesced across threads
        {
            float a = 0.f;
#pragma unroll 8
            for (int k = 0; k < 1152; k++) a += w1cT[(size_t)k * 256 + tid] * xrow[k];
            float sc = gc[tid] * rsqrtf(vc[tid] + EPSF);
            hsh[tid] = (a + b1c[tid] - mc[tid]) * sc + bbc[tid];
        }
        __syncthreads();
        // stage 2: thread j<144 owns logit j; w2cT[k][j] coalesced
        if (tid < 144) {
            float a = 0.f;
#pragma unroll 8
            for (int k = 0; k < 256; k++) a += w2cT[(size_t)k * 144 + tid] * hsh[k];
            Lsh[tid] = a + b2c[tid];
        }
        __syncthreads();
        if (tid == 0) {
            int bi = 0; float bv = Lsh[0];
            for (int j = 1; j < 144; j++) if (Lsh[j] > bv) { bv = Lsh[j]; bi = j; }
            amax[row] = bi;
        }
        __syncthreads();
    }
}

// ---------------------------------------------------------------------------
// gather patches from zero-padded x at argmax windows
// ---------------------------------------------------------------------------
__global__ __launch_bounds__(256) void gather_patches(const float* __restrict__ x,
    const int* __restrict__ amax, float* __restrict__ patches)
{
    int idx = blockIdx.x * 256 + threadIdx.x;
    int b = idx / 5760, j = idx - b * 5760;
    int c = j / 720, r2 = j - c * 720;
    int hh = r2 / 5, tw = r2 - hh * 5;
    int a = amax[b * 144 + hh];
    int w = a + tw - 2;
    patches[idx] = (w >= 0 && w < 144) ? x[(((size_t)(b * 8 + c) * 144 + hh) * 144) + w] : 0.f;
}

// ---------------------------------------------------------------------------
// tok GEMM, K-split into 8 chunks of 720 (deterministic 2-stage)
// ---------------------------------------------------------------------------
__global__ __launch_bounds__(256) void tok_partial(const float* __restrict__ patches,
    const float* __restrict__ tok_w, float* __restrict__ tpart)
{
    __shared__ float P[720];
    int b = blockIdx.x, ks = blockIdx.y, tid = threadIdx.x;
    for (int e = tid; e < 720; e += 256) P[e] = patches[(size_t)b * 5760 + ks * 720 + e];
    __syncthreads();
    float acc = 0.f;
    const float* wbase = tok_w + (size_t)ks * 720 * 256;
    for (int k = 0; k < 720; k++) acc += P[k] * wbase[(size_t)k * 256 + tid];
    tpart[((size_t)b * 8 + ks) * 256 + tid] = acc;
}

// ---------------------------------------------------------------------------
// attn_front: tok_finish + LN1(x6) + qkv (q only for token 5) + attention row 5
// + out-proj token 5 + residual + LN2.  One block per batch elem, 512 threads.
// ---------------------------------------------------------------------------
__global__ __launch_bounds__(512) void attn_front(
    const float* __restrict__ tpart, const float* __restrict__ tok_b,
    const float* __restrict__ emb,
    const float* __restrict__ ln1_g, const float* __restrict__ ln1_b,
    const float* __restrict__ qkv_w,
    const float* __restrict__ out_w, const float* __restrict__ out_b,
    const float* __restrict__ ln2_g, const float* __restrict__ ln2_b,
    float* __restrict__ z2_5, float* __restrict__ t5out)
{
    __shared__ float s[256];
    __shared__ float z[6][256];
    __shared__ float qk[6][192];   // cols: 0-63 q (row5 only), 64-127 k, 128-191 v
    __shared__ float att[2][6];
    __shared__ float o5[64];
    __shared__ float t5[256];
    __shared__ float stat[2];
    const int b = blockIdx.x, tid = threadIdx.x;
    const int lane = tid & 63, wv = tid >> 6;

    if (tid < 256) {
        float a = tok_b[tid];
        for (int ks = 0; ks < 8; ks++) a += tpart[((size_t)b * 8 + ks) * 256 + tid];
        s[tid] = a;
    }
    __syncthreads();

    // LN1: wave wv handles token wv (wv<6)
    if (wv < 6) {
        float y[4], s1 = 0.f, s2 = 0.f;
#pragma unroll
        for (int q = 0; q < 4; q++) {
            int k = lane + 64 * q;
            y[q] = s[k] + emb[wv * 256 + k];
            s1 += y[q]; s2 += y[q] * y[q];
        }
#pragma unroll
        for (int off = 32; off; off >>= 1) { s1 += __shfl_xor(s1, off); s2 += __shfl_xor(s2, off); }
        float mu = s1 * (1.f / 256.f);
        float var = s2 * (1.f / 256.f) - mu * mu;
        float rs = rsqrtf(var + EPSF);
#pragma unroll
        for (int q = 0; q < 4; q++) {
            int k = lane + 64 * q;
            z[wv][k] = (y[q] - mu) * rs * ln1_g[k] + ln1_b[k];
        }
    }
    __syncthreads();

    // qkv dots: d<768 -> k/v for token i=d>>7, col c=64+(d&127); d>=768 -> q5, c=d-768
    for (int d = tid; d < 832; d += 512) {
        int i, c;
        if (d < 768) { i = d >> 7; c = 64 + (d & 127); }
        else         { i = 5;      c = d - 768; }
        float a = 0.f;
#pragma unroll 4
        for (int k = 0; k < 256; k++) a += z[i][k] * qkv_w[(size_t)k * 192 + c];
        qk[i][c] = a;
    }
    __syncthreads();

    // attention row 5 only
    if (tid < 12) {
        int h = tid / 6, j = tid - h * 6;
        float a = 0.f;
#pragma unroll
        for (int d = 0; d < 32; d++) a += qk[5][h * 32 + d] * qk[j][64 + h * 32 + d];
        att[h][j] = a * 0.17677669529663687f;
    }
    __syncthreads();
    if (tid < 2) {
        float m = -3.0e38f;
        for (int j = 0; j < 6; j++) m = fmaxf(m, att[tid][j]);
        float ssum = 0.f;
        for (int j = 0; j < 6; j++) { float e = expf(att[tid][j] - m); att[tid][j] = e; ssum += e; }
        float inv = 1.f / ssum;
        for (int j = 0; j < 6; j++) att[tid][j] *= inv;
    }
    __syncthreads();
    if (tid < 64) {
        int h = tid >> 5;
        float a = 0.f;
#pragma unroll
        for (int j = 0; j < 6; j++) a += att[h][j] * qk[j][128 + tid];
        o5[tid] = a;
    }
    __syncthreads();

    // out-proj token 5 + residual
    if (tid < 256) {
        float a = out_b[tid] + s[tid] + emb[5 * 256 + tid];
#pragma unroll 4
        for (int d = 0; d < 64; d++) a += o5[d] * out_w[(size_t)d * 256 + tid];
        t5[tid] = a;
    }
    __syncthreads();

    // LN2 stats (wave 0)
    if (wv == 0) {
        float s1 = 0.f, s2 = 0.f;
#pragma unroll
        for (int q = 0; q < 4; q++) { float vv = t5[lane + 64 * q]; s1 += vv; s2 += vv * vv; }
#pragma unroll
        for (int off = 32; off; off >>= 1) { s1 += __shfl_xor(s1, off); s2 += __shfl_xor(s2, off); }
        if (lane == 0) {
            float mu = s1 * (1.f / 256.f);
            float var = s2 * (1.f / 256.f) - mu * mu;
            stat[0] = mu; stat[1] = rsqrtf(var + EPSF);
        }
    }
    __syncthreads();
    if (tid < 256) {
        t5out[(size_t)b * 256 + tid] = t5[tid];
        z2_5[(size_t)b * 256 + tid] = (t5[tid] - stat[0]) * stat[1] * ln2_g[tid] + ln2_b[tid];
    }
}

// ---------------------------------------------------------------------------
// ff1 + exact gelu for token 5: f5[b, jj] over N=512 split in 2 blocks
// ---------------------------------------------------------------------------
__global__ __launch_bounds__(256) void ff1_gelu(
    const float* __restrict__ z2_5, const float* __restrict__ ff_w1,
    const float* __restrict__ ff_b1, float* __restrict__ f5)
{
    __shared__ float zsh[256];
    const int b = blockIdx.x, half = blockIdx.y, tid = threadIdx.x;
    zsh[tid] = z2_5[(size_t)b * 256 + tid];
    __syncthreads();
    const int jj = half * 256 + tid;
    float a = ff_b1[jj];
#pragma unroll 4
    for (int k = 0; k < 256; k++) a += zsh[k] * ff_w1[(size_t)k * 512 + jj];
    f5[(size_t)b * 512 + jj] = 0.5f * a * (1.f + erff(a * 0.70710678118654752f));
}

// ---------------------------------------------------------------------------
// ff2 + residual + LNF for token 5 -> tfin
// ---------------------------------------------------------------------------
__global__ __launch_bounds__(256) void ff2_lnf(
    const float* __restrict__ f5, const float* __restrict__ ff_w2,
    const float* __restrict__ ff_b2, const float* __restrict__ t5in,
    const float* __restrict__ lnf_g, const float* __restrict__ lnf_b,
    float* __restrict__ tfin)
{
    __shared__ float fsh[512];
    __shared__ float tsh[256];
    __shared__ float stat[2];
    const int b = blockIdx.x, tid = threadIdx.x;
    const int lane = tid & 63;
    fsh[tid] = f5[(size_t)b * 512 + tid];
    fsh[tid + 256] = f5[(size_t)b * 512 + tid + 256];
    __syncthreads();
    float a = ff_b2[tid] + t5in[(size_t)b * 256 + tid];
#pragma unroll 4
    for (int k = 0; k < 512; k++) a += fsh[k] * ff_w2[(size_t)k * 256 + tid];
    tsh[tid] = a;
    __syncthreads();
    if (tid < 64) {
        float s1 = 0.f, s2 = 0.f;
#pragma unroll
        for (int q = 0; q < 4; q++) { float vv = tsh[lane + 64 * q]; s1 += vv; s2 += vv * vv; }
#pragma unroll
        for (int off = 32; off; off >>= 1) { s1 += __shfl_xor(s1, off); s2 += __shfl_xor(s2, off); }
        if (lane == 0) {
            float mu = s1 * (1.f / 256.f);
            float var = s2 * (1.f / 256.f) - mu * mu;
            stat[0] = mu; stat[1] = rsqrtf(var + EPSF);
        }
    }
    __syncthreads();
    tfin[(size_t)b * 256 + tid] = (tsh[tid] - stat[0]) * stat[1] * lnf_g[tid] + lnf_b[tid];
}

// ---------------------------------------------------------------------------
// fin GEMM for token 5: refined5[b,n] = tfin[b,:] @ fin_w[:,n] + fin_b[n]
// ---------------------------------------------------------------------------
__global__ __launch_bounds__(256) void fin_gemm(const float* __restrict__ tfin,
    const float* __restrict__ fin_w, const float* __restrict__ fin_b, float* __restrict__ refined5)
{
    __shared__ float tf[16][256];
    int tid = threadIdx.x;
    int nb = blockIdx.x * 256 + tid;
    int bg = blockIdx.y * 16;
    for (int e = tid; e < 4096; e += 256) tf[e >> 8][e & 255] = tfin[(size_t)(bg + (e >> 8)) * 256 + (e & 255)];
    __syncthreads();
    if (nb < 5760) {
        float acc[16];
#pragma unroll
        for (int bb = 0; bb < 16; bb++) acc[bb] = 0.f;
        for (int k = 0; k < 256; k++) {
            float wv = fin_w[(size_t)k * 5760 + nb];
#pragma unroll
            for (int bb = 0; bb < 16; bb++) acc[bb] += tf[bb][k] * wv;
        }
        float fb = fin_b[nb];
#pragma unroll
        for (int bb = 0; bb < 16; bb++)
            refined5[(size_t)(bg + bb) * 5760 + nb] = acc[bb] + fb;
    }
}

// ---------------------------------------------------------------------------
extern "C" void kernel_launch(void* const* d_in, const int* in_sizes, int n_in,
                              void* d_out, int out_size, void* d_ws, size_t ws_size,
                              hipStream_t stream)
{
    const float* x      = (const float*)d_in[0];
    const float* ext_w1 = (const float*)d_in[1];
    const float* ext_b1 = (const float*)d_in[2];
    const float* ext_g  = (const float*)d_in[3];
    const float* ext_bb = (const float*)d_in[4];
    const float* ext_m  = (const float*)d_in[5];
    const float* ext_v  = (const float*)d_in[6];
    const float* ext_w2 = (const float*)d_in[7];
    const float* ext_b2 = (const float*)d_in[8];
    const float* cls_w1 = (const float*)d_in[9];
    const float* cls_b1 = (const float*)d_in[10];
    const float* cls_g  = (const float*)d_in[11];
    const float* cls_bb = (const float*)d_in[12];
    const float* cls_m  = (const float*)d_in[13];
    const float* cls_v  = (const float*)d_in[14];
    const float* cls_w2 = (const float*)d_in[15];
    const float* cls_b2 = (const float*)d_in[16];
    const float* tok_w  = (const float*)d_in[17];
    const float* tok_b  = (const float*)d_in[18];
    const float* emb    = (const float*)d_in[19];
    const float* ln1_g  = (const float*)d_in[20];
    const float* ln1_b  = (const float*)d_in[21];
    const float* qkv_w  = (const float*)d_in[22];
    const float* out_w  = (const float*)d_in[23];
    const float* out_b  = (const float*)d_in[24];
    const float* ln2_g  = (const float*)d_in[25];
    const float* ln2_b  = (const float*)d_in[26];
    const float* ff_w1  = (const float*)d_in[27];
    const float* ff_b1  = (const float*)d_in[28];
    const float* ff_w2  = (const float*)d_in[29];
    const float* ff_b2  = (const float*)d_in[30];
    const float* lnf_g  = (const float*)d_in[31];
    const float* lnf_b  = (const float*)d_in[32];
    const float* fin_w  = (const float*)d_in[33];
    const float* fin_b  = (const float*)d_in[34];

    float* out = (float*)d_out;
    float* ws  = (float*)d_ws;

    // workspace layout (float offsets)
    float*  Wc32     = ws;                        // 184320
    float*  cconst   = ws + 184320;               // 160
    ushort* Wchi     = (ushort*)(ws + 184480);    // 184320 ushorts (92160 floats)
    ushort* Wclo     = (ushort*)(ws + 276640);    // 92160 floats
    float*  logitsP  = ws + 368800;               // 3*18432*160 = 8847360
    float*  partials = ws + 9216160;              // 4608
    float*  patches  = ws + 9220768;              // 737280
    float*  z2_5     = ws + 9958048;              // 32768
    float*  t5buf    = ws + 9990816;              // 32768
    float*  f5buf    = ws + 10023584;             // 65536
    float*  tfin     = ws + 10089120;             // 32768
    float*  refined5 = ws + 10121888;             // 737280
    float*  tpart    = ws + 10859168;             // 262144
    int*    amax     = (int*)(ws + 11121312);     // 18432
    int*    flag     = (int*)(ws + 11139744);     // 1
    int*    cand_cnt = (int*)(ws + 11139745);     // 1
    int*    cand_lst = (int*)(ws + 11139746);     // 18432
    float*  w1cT     = ws + 11158180;             // 294912
    float*  w2cT     = ws + 11453092;             // 36864 -> ends 11489956

    // output offsets: ext | cls | ext2 | cls2
    float* out_ext  = out;
    float* out_cls  = out + 36864;
    float* out_ext2 = out + 2691072;
    float* out_cls2 = out + 2727936;

    dim3 blk(256);

    // combined weights + transposed fixup weights (independent of x)
    wcomb_build<<<160, blk, 0, stream>>>(
        ext_w1, ext_b1, ext_g, ext_bb, ext_m, ext_v, ext_w2, ext_b2,
        cls_w1, cls_b1, cls_g, cls_bb, cls_m, cls_v, cls_w2, cls_b2,
        Wc32, Wchi, Wclo, cconst);
    zero_counters<<<1, 1, 0, stream>>>(cand_cnt);
    transpose_w<<<dim3(36, 8), blk, 0, stream>>>(cls_w1, w1cT, 256, 1152);
    transpose_w<<<dim3(8, 5), blk, 0, stream>>>(cls_w2, w2cT, 144, 256);

    // pass 1
    logits_gemm<0><<<dim3(576, NKS), blk, 0, stream>>>(x, Wchi, Wclo,
        nullptr, nullptr, nullptr, logitsP);
    softmax_heads<<<4608, blk, 0, stream>>>(logitsP, cconst, out_cls, out_ext, amax, partials,
        cand_cnt, cand_lst);
    reduce_flag<<<1, blk, 0, stream>>>(partials, 4608, flag);
    fixup_list<<<256, blk, 0, stream>>>(cand_cnt, cand_lst, x,
        w1cT, cls_b1, cls_g, cls_bb, cls_m, cls_v, w2cT, cls_b2, amax);

    // refine chain (always computed; application predicated on flag)
    gather_patches<<<2880, blk, 0, stream>>>(x, amax, patches);
    tok_partial<<<dim3(128, 8), blk, 0, stream>>>(patches, tok_w, tpart);
    attn_front<<<128, dim3(512), 0, stream>>>(tpart, tok_b, emb, ln1_g, ln1_b, qkv_w,
        out_w, out_b, ln2_g, ln2_b, z2_5, t5buf);
    ff1_gelu<<<dim3(128, 2), blk, 0, stream>>>(z2_5, ff_w1, ff_b1, f5buf);
    ff2_lnf<<<128, blk, 0, stream>>>(f5buf, ff_w2, ff_b2, t5buf, lnf_g, lnf_b, tfin);
    fin_gemm<<<dim3(23, 8), blk, 0, stream>>>(tfin, fin_w, fin_b, refined5);

    // pass 2 (x2 patched on the fly)
    logits_gemm<1><<<dim3(576, NKS), blk, 0, stream>>>(x, Wchi, Wclo,
        amax, refined5, flag, logitsP);
    softmax_heads<<<4608, blk, 0, stream>>>(logitsP, cconst, out_cls2, out_ext2, nullptr, nullptr,
        nullptr, nullptr);
}

// Round 10
// 368.842 us; speedup vs baseline: 1.4043x; 1.4043x over previous
//
#include <hip/hip_runtime.h>
#include <math.h>

#define EPSF 1e-5f
#define GAPTH 1e-3f
#define NKS 3           // K-split slices for logits GEMM
#define RROWS 18432

// B=128, C=8, H=144, W=144, CW=1152, R=18432, TW=5, OG=2, NCLS=6, DT=256, ITC=5760
// Collapsed head: logits[row, j] = sum_k Wc[j,k] * x'[row,k] + cconst[j]
//   j 0..143 = cls, j 144..145 = ext, j 146..159 = zero pad. NP=160.
// Pass 2 = pass 1 + rank-40 per-row delta (only argmax window columns change).

typedef __attribute__((ext_vector_type(8))) short short8v;
typedef __attribute__((ext_vector_type(4))) float f32x4;
typedef unsigned short ushort;
typedef unsigned int uint;

__device__ inline ushort f2bf(float f) {
    uint u = __float_as_uint(f);
    uint r = (u + 0x7FFFu + ((u >> 16) & 1u)) >> 16;
    return (ushort)r;
}
__device__ inline float bf2f(ushort h) { return __uint_as_float(((uint)h) << 16); }

// ---------------------------------------------------------------------------
// Build combined weights: Wc[j,k] = sum_o w2[j,o]*s[o]*w1[o,k], s = g*rsqrt(v+eps)
// cconst[j] = sum_o w2[j,o]*((b1[o]-m[o])*s[o]+bb[o]) + b2[j].  Also bf16 hi/lo.
// ---------------------------------------------------------------------------
__global__ __launch_bounds__(256) void wcomb_build(
    const float* __restrict__ w1e, const float* __restrict__ b1e, const float* __restrict__ ge,
    const float* __restrict__ bbe, const float* __restrict__ me, const float* __restrict__ ve,
    const float* __restrict__ w2e, const float* __restrict__ b2e,
    const float* __restrict__ w1c, const float* __restrict__ b1c, const float* __restrict__ gc,
    const float* __restrict__ bbc, const float* __restrict__ mc, const float* __restrict__ vc,
    const float* __restrict__ w2c, const float* __restrict__ b2c,
    float* __restrict__ Wc32, ushort* __restrict__ Wchi, ushort* __restrict__ Wclo,
    float* __restrict__ cconst)
{
    __shared__ float coef[256];
    __shared__ float csum[4];
    const int j = blockIdx.x, tid = threadIdx.x;
    const int lane = tid & 63, wid = tid >> 6;

    const float *w1 = nullptr, *w2row = nullptr, *b1 = nullptr, *g = nullptr,
                *bb = nullptr, *m = nullptr, *v = nullptr;
    float b2v = 0.f;
    int valid = 0;
    if (j < 144) {
        valid = 1; w1 = w1c; w2row = w2c + (size_t)j * 256;
        b1 = b1c; g = gc; bb = bbc; m = mc; v = vc; b2v = b2c[j];
    } else if (j < 146) {
        valid = 1; w1 = w1e; w2row = w2e + (size_t)(j - 144) * 256;
        b1 = b1e; g = ge; bb = bbe; m = me; v = ve; b2v = b2e[j - 144];
    }

    float cf = 0.f, cc = 0.f;
    if (valid) {
        float s = g[tid] * rsqrtf(v[tid] + EPSF);
        float w2v = w2row[tid];
        cf = w2v * s;
        cc = w2v * ((b1[tid] - m[tid]) * s + bb[tid]);
    }
    coef[tid] = cf;
    float t = cc;
#pragma unroll
    for (int off = 32; off; off >>= 1) t += __shfl_xor(t, off);
    if (lane == 0) csum[wid] = t;
    __syncthreads();
    if (tid == 0) cconst[j] = valid ? ((csum[0] + csum[1]) + (csum[2] + csum[3]) + b2v) : 0.f;

    for (int k = tid; k < 1152; k += 256) {
        float acc = 0.f;
        if (valid) {
            for (int o = 0; o < 256; o++) acc += coef[o] * w1[(size_t)o * 1152 + k];
        }
        Wc32[(size_t)j * 1152 + k] = acc;
        ushort hi = f2bf(acc);
        Wchi[(size_t)j * 1152 + k] = hi;
        Wclo[(size_t)j * 1152 + k] = f2bf(acc - bf2f(hi));
    }
}

__global__ void zero_counters(int* __restrict__ cand_count)
{
    *cand_count = 0;
}

// ---------------------------------------------------------------------------
// tiled transpose: src[R][Cc] -> dst[Cc][R]
// ---------------------------------------------------------------------------
__global__ __launch_bounds__(256) void transpose_w(
    const float* __restrict__ src, float* __restrict__ dst, int R, int Cc)
{
    __shared__ float tile[32][33];
    const int rb = blockIdx.y * 32, cb = blockIdx.x * 32;
    const int tx = threadIdx.x & 31, ty = threadIdx.x >> 5;   // ty 0..7
#pragma unroll
    for (int i = ty; i < 32; i += 8) {
        int r = rb + i, c = cb + tx;
        tile[i][tx] = (r < R && c < Cc) ? src[(size_t)r * Cc + c] : 0.f;
    }
    __syncthreads();
#pragma unroll
    for (int i = ty; i < 32; i += 8) {
        int c = cb + i, r = rb + tx;
        if (c < Cc && r < R) dst[(size_t)c * R + r] = tile[tx][i];
    }
}

// ---------------------------------------------------------------------------
// logits GEMM (pass 1 only): M=18432, N=160(146 used), K=1152 in NKS slices.
// Split-bf16 MFMA (hi/lo, 3 products). BM=64, BN=160, BK=32; 4 waves 2m x 2n.
// Writes per-slice partials (no cconst); softmax sums slices.
// ---------------------------------------------------------------------------
__global__ __launch_bounds__(256) void logits_gemm(
    const float* __restrict__ x, const ushort* __restrict__ Wchi, const ushort* __restrict__ Wclo,
    float* __restrict__ logits_part)
{
    __shared__ ushort Ahi[64][40], Alo[64][40], Bhi[160][40], Blo[160][40];
    const int tid = threadIdx.x;
    const int lane = tid & 63, wid = tid >> 6;
    const int wm = wid & 1, wn = wid >> 1;
    const int rb = blockIdx.x * 64;
    const int ks = blockIdx.y;
    const int kbase = ks * (1152 / NKS);        // 384 per slice
    const int NIT = (1152 / NKS) / 32;          // 12

    // A staging coords (fixed per thread): 8 contiguous k per thread
    const int rl = tid >> 2, kk = (tid & 3) << 3;
    const int arow = rb + rl;
    const int ab = arow / 144, ahh = arow - ab * 144;

    // B staging coords
    const int br0 = tid >> 2, bk0 = (tid & 3) << 3;          // rows 0..63 (+64..127)
    const int br2 = 128 + (tid >> 2), bk2 = (tid & 3) << 3;  // rows 128..159 (tid<128)

    float av[8];
    short8v vbh0, vbl0, vbh1, vbl1, vbh2, vbl2;

    auto LOAD = [&](int kb) {
        int k1 = kb + kk, c1 = k1 / 144, w1 = k1 - c1 * 144;
        const float4 t0 = *reinterpret_cast<const float4*>(
            x + (((size_t)(ab * 8 + c1) * 144 + ahh) * 144 + w1));
        int k2 = k1 + 4, c2 = k2 / 144, w2 = k2 - c2 * 144;
        const float4 t1 = *reinterpret_cast<const float4*>(
            x + (((size_t)(ab * 8 + c2) * 144 + ahh) * 144 + w2));
        av[0] = t0.x; av[1] = t0.y; av[2] = t0.z; av[3] = t0.w;
        av[4] = t1.x; av[5] = t1.y; av[6] = t1.z; av[7] = t1.w;
        size_t o0 = (size_t)br0 * 1152 + kb + bk0;
        vbh0 = *reinterpret_cast<const short8v*>(Wchi + o0);
        vbl0 = *reinterpret_cast<const short8v*>(Wclo + o0);
        size_t o1 = (size_t)(br0 + 64) * 1152 + kb + bk0;
        vbh1 = *reinterpret_cast<const short8v*>(Wchi + o1);
        vbl1 = *reinterpret_cast<const short8v*>(Wclo + o1);
        if (tid < 128) {
            size_t o2 = (size_t)br2 * 1152 + kb + bk2;
            vbh2 = *reinterpret_cast<const short8v*>(Wchi + o2);
            vbl2 = *reinterpret_cast<const short8v*>(Wclo + o2);
        }
    };

    auto STORE = [&]() {
        short8v hv, lv;
#pragma unroll
        for (int q = 0; q < 8; q++) {
            ushort h = f2bf(av[q]);
            hv[q] = (short)h;
            lv[q] = (short)f2bf(av[q] - bf2f(h));
        }
        *reinterpret_cast<short8v*>(&Ahi[rl][kk]) = hv;
        *reinterpret_cast<short8v*>(&Alo[rl][kk]) = lv;
        *reinterpret_cast<short8v*>(&Bhi[br0][bk0]) = vbh0;
        *reinterpret_cast<short8v*>(&Blo[br0][bk0]) = vbl0;
        *reinterpret_cast<short8v*>(&Bhi[br0 + 64][bk0]) = vbh1;
        *reinterpret_cast<short8v*>(&Blo[br0 + 64][bk0]) = vbl1;
        if (tid < 128) {
            *reinterpret_cast<short8v*>(&Bhi[br2][bk2]) = vbh2;
            *reinterpret_cast<short8v*>(&Blo[br2][bk2]) = vbl2;
        }
    };

    f32x4 acc[2][5];
#pragma unroll
    for (int mt = 0; mt < 2; mt++)
#pragma unroll
        for (int nt = 0; nt < 5; nt++) acc[mt][nt] = (f32x4){0.f, 0.f, 0.f, 0.f};

    const int fr = lane & 15, fg = (lane >> 4) << 3;

    LOAD(kbase);
    for (int t = 0; t < NIT; t++) {
        STORE();
        if (t < NIT - 1) LOAD(kbase + (t + 1) * 32);
        __syncthreads();
        short8v ah0 = *reinterpret_cast<const short8v*>(&Ahi[wm * 32 + fr][fg]);
        short8v al0 = *reinterpret_cast<const short8v*>(&Alo[wm * 32 + fr][fg]);
        short8v ah1 = *reinterpret_cast<const short8v*>(&Ahi[wm * 32 + 16 + fr][fg]);
        short8v al1 = *reinterpret_cast<const short8v*>(&Alo[wm * 32 + 16 + fr][fg]);
#pragma unroll
        for (int nt = 0; nt < 5; nt++) {
            short8v bh = *reinterpret_cast<const short8v*>(&Bhi[wn * 80 + nt * 16 + fr][fg]);
            short8v bl = *reinterpret_cast<const short8v*>(&Blo[wn * 80 + nt * 16 + fr][fg]);
            acc[0][nt] = __builtin_amdgcn_mfma_f32_16x16x32_bf16(ah0, bh, acc[0][nt], 0, 0, 0);
            acc[0][nt] = __builtin_amdgcn_mfma_f32_16x16x32_bf16(ah0, bl, acc[0][nt], 0, 0, 0);
            acc[0][nt] = __builtin_amdgcn_mfma_f32_16x16x32_bf16(al0, bh, acc[0][nt], 0, 0, 0);
            acc[1][nt] = __builtin_amdgcn_mfma_f32_16x16x32_bf16(ah1, bh, acc[1][nt], 0, 0, 0);
            acc[1][nt] = __builtin_amdgcn_mfma_f32_16x16x32_bf16(ah1, bl, acc[1][nt], 0, 0, 0);
            acc[1][nt] = __builtin_amdgcn_mfma_f32_16x16x32_bf16(al1, bh, acc[1][nt], 0, 0, 0);
        }
        __syncthreads();
    }

    // epilogue: C/D layout col=lane&15, row=(lane>>4)*4+i  [m89-verified]
    float* base = logits_part + (size_t)ks * RROWS * 160;
#pragma unroll
    for (int mt = 0; mt < 2; mt++) {
#pragma unroll
        for (int nt = 0; nt < 5; nt++) {
            int gcol = wn * 80 + nt * 16 + fr;
            if (gcol < 146) {
                float* dst = base + (size_t)(rb + wm * 32 + mt * 16 + ((lane >> 4) << 2)) * 160 + gcol;
#pragma unroll
                for (int i = 0; i < 4; i++)
                    dst[(size_t)i * 160] = acc[mt][nt][i];
            }
        }
    }
}

// ---------------------------------------------------------------------------
// delta_logits: logits_part[0] += WcT[:,j] dot (refined5 - x) over the 40
// patched k-positions (8 channels x 5-window at this row's argmax col).
// Exact f32. No-op when *flag == 0 (pass 2 logits == pass 1 logits).
// One wave per row, 4 rows per block.
// ---------------------------------------------------------------------------
__global__ __launch_bounds__(256) void delta_logits(
    const float* __restrict__ x, const float* __restrict__ WcT,
    const int* __restrict__ amax, const float* __restrict__ refined5,
    const int* __restrict__ flag, float* __restrict__ logits_part)
{
    if (*flag == 0) return;
    __shared__ float dsh[4][40];
    __shared__ int   ksh[4][40];
    const int r4 = threadIdx.x >> 6, lane = threadIdx.x & 63;
    const int row = blockIdx.x * 4 + r4;
    const int b = row / 144, hh = row - b * 144;
    const int a = amax[row];
    if (lane < 40) {
        int c = lane / 5, tw = lane - c * 5;
        int w = a - 2 + tw;
        float d = 0.f; int k = 0;
        if (w >= 0 && w < 144) {
            k = c * 144 + w;
            d = refined5[(size_t)b * 5760 + (c * 144 + hh) * 5 + tw]
              - x[((size_t)(b * 8 + c) * 144 + hh) * 144 + w];
        }
        dsh[r4][lane] = d; ksh[r4][lane] = k;
    }
    __syncthreads();
    float* L = logits_part + (size_t)row * 160;
#pragma unroll
    for (int rj = 0; rj < 3; rj++) {
        int j = lane + rj * 64;
        if (j < 146) {
            float acc = 0.f;
#pragma unroll 8
            for (int i = 0; i < 40; i++)
                acc += WcT[(size_t)ksh[r4][i] * 160 + j] * dsh[r4][i];
            L[j] += acc;
        }
    }
}

// ---------------------------------------------------------------------------
// merged softmax over summed K-slices: cls cols 0..143 (+argmax & gap->cands),
// ext cols 144..145.  One wave per row, 4 rows per block.
// ---------------------------------------------------------------------------
__global__ __launch_bounds__(256) void softmax_heads(
    const float* __restrict__ logits_part, const float* __restrict__ cconst,
    float* __restrict__ out_cls, float* __restrict__ out_ext,
    int* __restrict__ amax, float* __restrict__ partials,
    int* __restrict__ cand_count, int* __restrict__ cand_list)
{
    __shared__ float ps[4];
    int row = blockIdx.x * 4 + (threadIdx.x >> 6);
    int lane = threadIdx.x & 63;
    const float* L0 = logits_part + (size_t)row * 160;
    const float* L1 = L0 + (size_t)RROWS * 160;
    const float* L2 = L1 + (size_t)RROWS * 160;
    float v0 = L0[lane] + L1[lane] + L2[lane] + cconst[lane];
    float v1 = L0[lane + 64] + L1[lane + 64] + L2[lane + 64] + cconst[lane + 64];
    float v2 = (lane < 16) ? (L0[lane + 128] + L1[lane + 128] + L2[lane + 128] + cconst[lane + 128])
                           : -3.0e38f;
    // argmax (first-max tie rule) + top-2 values
    float m = v0; int mi = lane;
    if (v1 > m) { m = v1; mi = lane + 64; }
    if (v2 > m) { m = v2; mi = lane + 128; }
    float m1 = v0, m2 = -3.0e38f;
    if (v1 > m1) { m2 = m1; m1 = v1; } else m2 = v1;
    if (v2 > m1) { m2 = m1; m1 = v2; } else m2 = fmaxf(m2, v2);
#pragma unroll
    for (int off = 32; off; off >>= 1) {
        float om = __shfl_xor(m, off);
        int   oi = __shfl_xor(mi, off);
        if (om > m || (om == m && oi < mi)) { m = om; mi = oi; }
        float om1 = __shfl_xor(m1, off);
        float om2 = __shfl_xor(m2, off);
        float nm1 = fmaxf(m1, om1);
        m2 = fmaxf(fminf(m1, om1), fmaxf(m2, om2));
        m1 = nm1;
    }
    float e0 = expf(v0 - m), e1 = expf(v1 - m);
    float e2 = (lane < 16) ? expf(v2 - m) : 0.f;
    float s = e0 + e1 + e2;
#pragma unroll
    for (int off = 32; off; off >>= 1) s += __shfl_xor(s, off);
    float inv = 1.f / s;
    float* O = out_cls + (size_t)row * 144;
    O[lane] = e0 * inv;
    O[lane + 64] = e1 * inv;
    if (lane < 16) O[lane + 128] = e2 * inv;

    // ext head (2 logits)
    float l0 = L0[144] + L1[144] + L2[144] + cconst[144];
    float l1 = L0[145] + L1[145] + L2[145] + cconst[145];
    float mx = fmaxf(l0, l1);
    float ee0 = expf(l0 - mx), ee1 = expf(l1 - mx);
    float einv = 1.f / (ee0 + ee1);
    float p0 = ee0 * einv;
    if (lane == 0) {
        out_ext[(size_t)row * 2] = p0;
        out_ext[(size_t)row * 2 + 1] = ee1 * einv;
        if (amax != nullptr) {
            amax[row] = mi;
            if (m1 - m2 < GAPTH) {
                int slot = atomicAdd(cand_count, 1);
                cand_list[slot] = row;
            }
        }
    }
    if (partials != nullptr) {
        if (lane == 0) ps[threadIdx.x >> 6] = p0;
        __syncthreads();
        if (threadIdx.x == 0) partials[blockIdx.x] = (ps[0] + ps[1]) + (ps[2] + ps[3]);
    }
}

__global__ __launch_bounds__(256) void reduce_flag(const float* __restrict__ partials, int n,
                                                   int* __restrict__ flag)
{
    __shared__ float sm[256];
    int tid = threadIdx.x;
    float s = 0.f;
    for (int i = tid; i < n; i += 256) s += partials[i];
    sm[tid] = s; __syncthreads();
    for (int off = 128; off; off >>= 1) {
        if (tid < off) sm[tid] += sm[tid + off];
        __syncthreads();
    }
    if (tid == 0) *flag = (sm[0] * (1.f / 18432.f) > 0.3f) ? 1 : 0;
}

// ---------------------------------------------------------------------------
// fixup over compacted candidate list: exact f32 two-stage recompute of argmax.
// Transposed weights -> per-k coalesced loads, thread-parallel dots.
// ---------------------------------------------------------------------------
__global__ __launch_bounds__(256) void fixup_list(
    const int* __restrict__ cand_count, const int* __restrict__ cand_list,
    const float* __restrict__ x,
    const float* __restrict__ w1cT, const float* __restrict__ b1c,
    const float* __restrict__ gc, const float* __restrict__ bbc,
    const float* __restrict__ mc, const float* __restrict__ vc,
    const float* __restrict__ w2cT, const float* __restrict__ b2c,
    int* __restrict__ amax)
{
    __shared__ float xrow[1152];
    __shared__ float hsh[256];
    __shared__ float Lsh[144];
    const int tid = threadIdx.x;
    const int n = *cand_count;

    for (int ci = blockIdx.x; ci < n; ci += gridDim.x) {
        const int row = cand_list[ci];
        const int b = row / 144, hh = row - b * 144;
        for (int e = tid; e < 1152; e += 256) {
            int c = e / 144, w = e - c * 144;
            xrow[e] = x[(((size_t)(b * 8 + c) * 144 + hh) * 144) + w];
        }
        __syncthreads();
        {
            float a = 0.f;
#pragma unroll 8
            for (int k = 0; k < 1152; k++) a += w1cT[(size_t)k * 256 + tid] * xrow[k];
            float sc = gc[tid] * rsqrtf(vc[tid] + EPSF);
            hsh[tid] = (a + b1c[tid] - mc[tid]) * sc + bbc[tid];
        }
        __syncthreads();
        if (tid < 144) {
            float a = 0.f;
#pragma unroll 8
            for (int k = 0; k < 256; k++) a += w2cT[(size_t)k * 144 + tid] * hsh[k];
            Lsh[tid] = a + b2c[tid];
        }
        __syncthreads();
        if (tid == 0) {
            int bi = 0; float bv = Lsh[0];
            for (int j = 1; j < 144; j++) if (Lsh[j] > bv) { bv = Lsh[j]; bi = j; }
            amax[row] = bi;
        }
        __syncthreads();
    }
}

// ---------------------------------------------------------------------------
// gather patches from zero-padded x at argmax windows
// ---------------------------------------------------------------------------
__global__ __launch_bounds__(256) void gather_patches(const float* __restrict__ x,
    const int* __restrict__ amax, float* __restrict__ patches)
{
    int idx = blockIdx.x * 256 + threadIdx.x;
    int b = idx / 5760, j = idx - b * 5760;
    int c = j / 720, r2 = j - c * 720;
    int hh = r2 / 5, tw = r2 - hh * 5;
    int a = amax[b * 144 + hh];
    int w = a + tw - 2;
    patches[idx] = (w >= 0 && w < 144) ? x[(((size_t)(b * 8 + c) * 144 + hh) * 144) + w] : 0.f;
}

// ---------------------------------------------------------------------------
// tok GEMM, K-split into 8 chunks of 720 (deterministic 2-stage)
// ---------------------------------------------------------------------------
__global__ __launch_bounds__(256) void tok_partial(const float* __restrict__ patches,
    const float* __restrict__ tok_w, float* __restrict__ tpart)
{
    __shared__ float P[720];
    int b = blockIdx.x, ks = blockIdx.y, tid = threadIdx.x;
    for (int e = tid; e < 720; e += 256) P[e] = patches[(size_t)b * 5760 + ks * 720 + e];
    __syncthreads();
    float acc = 0.f;
    const float* wbase = tok_w + (size_t)ks * 720 * 256;
    for (int k = 0; k < 720; k++) acc += P[k] * wbase[(size_t)k * 256 + tid];
    tpart[((size_t)b * 8 + ks) * 256 + tid] = acc;
}

// ---------------------------------------------------------------------------
// attn_front: tok_finish + LN1(x6) + qkv (q only for token 5) + attention row 5
// + out-proj token 5 + residual + LN2.  One block per batch elem, 512 threads.
// ---------------------------------------------------------------------------
__global__ __launch_bounds__(512) void attn_front(
    const float* __restrict__ tpart, const float* __restrict__ tok_b,
    const float* __restrict__ emb,
    const float* __restrict__ ln1_g, const float* __restrict__ ln1_b,
    const float* __restrict__ qkv_w,
    const float* __restrict__ out_w, const float* __restrict__ out_b,
    const float* __restrict__ ln2_g, const float* __restrict__ ln2_b,
    float* __restrict__ z2_5, float* __restrict__ t5out)
{
    __shared__ float s[256];
    __shared__ float z[6][256];
    __shared__ float qk[6][192];   // cols: 0-63 q (row5 only), 64-127 k, 128-191 v
    __shared__ float att[2][6];
    __shared__ float o5[64];
    __shared__ float t5[256];
    __shared__ float stat[2];
    const int b = blockIdx.x, tid = threadIdx.x;
    const int lane = tid & 63, wv = tid >> 6;

    if (tid < 256) {
        float a = tok_b[tid];
        for (int ks = 0; ks < 8; ks++) a += tpart[((size_t)b * 8 + ks) * 256 + tid];
        s[tid] = a;
    }
    __syncthreads();

    // LN1: wave wv handles token wv (wv<6)
    if (wv < 6) {
        float y[4], s1 = 0.f, s2 = 0.f;
#pragma unroll
        for (int q = 0; q < 4; q++) {
            int k = lane + 64 * q;
            y[q] = s[k] + emb[wv * 256 + k];
            s1 += y[q]; s2 += y[q] * y[q];
        }
#pragma unroll
        for (int off = 32; off; off >>= 1) { s1 += __shfl_xor(s1, off); s2 += __shfl_xor(s2, off); }
        float mu = s1 * (1.f / 256.f);
        float var = s2 * (1.f / 256.f) - mu * mu;
        float rs = rsqrtf(var + EPSF);
#pragma unroll
        for (int q = 0; q < 4; q++) {
            int k = lane + 64 * q;
            z[wv][k] = (y[q] - mu) * rs * ln1_g[k] + ln1_b[k];
        }
    }
    __syncthreads();

    // qkv dots: d<768 -> k/v for token i=d>>7, col c=64+(d&127); d>=768 -> q5, c=d-768
    for (int d = tid; d < 832; d += 512) {
        int i, c;
        if (d < 768) { i = d >> 7; c = 64 + (d & 127); }
        else         { i = 5;      c = d - 768; }
        float a = 0.f;
#pragma unroll 4
        for (int k = 0; k < 256; k++) a += z[i][k] * qkv_w[(size_t)k * 192 + c];
        qk[i][c] = a;
    }
    __syncthreads();

    // attention row 5 only
    if (tid < 12) {
        int h = tid / 6, j = tid - h * 6;
        float a = 0.f;
#pragma unroll
        for (int d = 0; d < 32; d++) a += qk[5][h * 32 + d] * qk[j][64 + h * 32 + d];
        att[h][j] = a * 0.17677669529663687f;
    }
    __syncthreads();
    if (tid < 2) {
        float m = -3.0e38f;
        for (int j = 0; j < 6; j++) m = fmaxf(m, att[tid][j]);
        float ssum = 0.f;
        for (int j = 0; j < 6; j++) { float e = expf(att[tid][j] - m); att[tid][j] = e; ssum += e; }
        float inv = 1.f / ssum;
        for (int j = 0; j < 6; j++) att[tid][j] *= inv;
    }
    __syncthreads();
    if (tid < 64) {
        int h = tid >> 5;
        float a = 0.f;
#pragma unroll
        for (int j = 0; j < 6; j++) a += att[h][j] * qk[j][128 + tid];
        o5[tid] = a;
    }
    __syncthreads();

    // out-proj token 5 + residual
    if (tid < 256) {
        float a = out_b[tid] + s[tid] + emb[5 * 256 + tid];
#pragma unroll 4
        for (int d = 0; d < 64; d++) a += o5[d] * out_w[(size_t)d * 256 + tid];
        t5[tid] = a;
    }
    __syncthreads();

    // LN2 stats (wave 0)
    if (wv == 0) {
        float s1 = 0.f, s2 = 0.f;
#pragma unroll
        for (int q = 0; q < 4; q++) { float vv = t5[lane + 64 * q]; s1 += vv; s2 += vv * vv; }
#pragma unroll
        for (int off = 32; off; off >>= 1) { s1 += __shfl_xor(s1, off); s2 += __shfl_xor(s2, off); }
        if (lane == 0) {
            float mu = s1 * (1.f / 256.f);
            float var = s2 * (1.f / 256.f) - mu * mu;
            stat[0] = mu; stat[1] = rsqrtf(var + EPSF);
        }
    }
    __syncthreads();
    if (tid < 256) {
        t5out[(size_t)b * 256 + tid] = t5[tid];
        z2_5[(size_t)b * 256 + tid] = (t5[tid] - stat[0]) * stat[1] * ln2_g[tid] + ln2_b[tid];
    }
}

// ---------------------------------------------------------------------------
// ff1 + exact gelu for token 5: f5[b, jj] over N=512 split in 2 blocks
// ---------------------------------------------------------------------------
__global__ __launch_bounds__(256) void ff1_gelu(
    const float* __restrict__ z2_5, const float* __restrict__ ff_w1,
    const float* __restrict__ ff_b1, float* __restrict__ f5)
{
    __shared__ float zsh[256];
    const int b = blockIdx.x, half = blockIdx.y, tid = threadIdx.x;
    zsh[tid] = z2_5[(size_t)b * 256 + tid];
    __syncthreads();
    const int jj = half * 256 + tid;
    float a = ff_b1[jj];
#pragma unroll 4
    for (int k = 0; k < 256; k++) a += zsh[k] * ff_w1[(size_t)k * 512 + jj];
    f5[(size_t)b * 512 + jj] = 0.5f * a * (1.f + erff(a * 0.70710678118654752f));
}

// ---------------------------------------------------------------------------
// ff2 + residual + LNF for token 5 -> tfin
// ---------------------------------------------------------------------------
__global__ __launch_bounds__(256) void ff2_lnf(
    const float* __restrict__ f5, const float* __restrict__ ff_w2,
    const float* __restrict__ ff_b2, const float* __restrict__ t5in,
    const float* __restrict__ lnf_g, const float* __restrict__ lnf_b,
    float* __restrict__ tfin)
{
    __shared__ float fsh[512];
    __shared__ float tsh[256];
    __shared__ float stat[2];
    const int b = blockIdx.x, tid = threadIdx.x;
    const int lane = tid & 63;
    fsh[tid] = f5[(size_t)b * 512 + tid];
    fsh[tid + 256] = f5[(size_t)b * 512 + tid + 256];
    __syncthreads();
    float a = ff_b2[tid] + t5in[(size_t)b * 256 + tid];
#pragma unroll 4
    for (int k = 0; k < 512; k++) a += fsh[k] * ff_w2[(size_t)k * 256 + tid];
    tsh[tid] = a;
    __syncthreads();
    if (tid < 64) {
        float s1 = 0.f, s2 = 0.f;
#pragma unroll
        for (int q = 0; q < 4; q++) { float vv = tsh[lane + 64 * q]; s1 += vv; s2 += vv * vv; }
#pragma unroll
        for (int off = 32; off; off >>= 1) { s1 += __shfl_xor(s1, off); s2 += __shfl_xor(s2, off); }
        if (lane == 0) {
            float mu = s1 * (1.f / 256.f);
            float var = s2 * (1.f / 256.f) - mu * mu;
            stat[0] = mu; stat[1] = rsqrtf(var + EPSF);
        }
    }
    __syncthreads();
    tfin[(size_t)b * 256 + tid] = (tsh[tid] - stat[0]) * stat[1] * lnf_g[tid] + lnf_b[tid];
}

// ---------------------------------------------------------------------------
// fin GEMM for token 5: refined5[b,n] = tfin[b,:] @ fin_w[:,n] + fin_b[n]
// ---------------------------------------------------------------------------
__global__ __launch_bounds__(256) void fin_gemm(const float* __restrict__ tfin,
    const float* __restrict__ fin_w, const float* __restrict__ fin_b, float* __restrict__ refined5)
{
    __shared__ float tf[16][256];
    int tid = threadIdx.x;
    int nb = blockIdx.x * 256 + tid;
    int bg = blockIdx.y * 16;
    for (int e = tid; e < 4096; e += 256) tf[e >> 8][e & 255] = tfin[(size_t)(bg + (e >> 8)) * 256 + (e & 255)];
    __syncthreads();
    if (nb < 5760) {
        float acc[16];
#pragma unroll
        for (int bb = 0; bb < 16; bb++) acc[bb] = 0.f;
        for (int k = 0; k < 256; k++) {
            float wv = fin_w[(size_t)k * 5760 + nb];
#pragma unroll
            for (int bb = 0; bb < 16; bb++) acc[bb] += tf[bb][k] * wv;
        }
        float fb = fin_b[nb];
#pragma unroll
        for (int bb = 0; bb < 16; bb++)
            refined5[(size_t)(bg + bb) * 5760 + nb] = acc[bb] + fb;
    }
}

// ---------------------------------------------------------------------------
extern "C" void kernel_launch(void* const* d_in, const int* in_sizes, int n_in,
                              void* d_out, int out_size, void* d_ws, size_t ws_size,
                              hipStream_t stream)
{
    const float* x      = (const float*)d_in[0];
    const float* ext_w1 = (const float*)d_in[1];
    const float* ext_b1 = (const float*)d_in[2];
    const float* ext_g  = (const float*)d_in[3];
    const float* ext_bb = (const float*)d_in[4];
    const float* ext_m  = (const float*)d_in[5];
    const float* ext_v  = (const float*)d_in[6];
    const float* ext_w2 = (const float*)d_in[7];
    const float* ext_b2 = (const float*)d_in[8];
    const float* cls_w1 = (const float*)d_in[9];
    const float* cls_b1 = (const float*)d_in[10];
    const float* cls_g  = (const float*)d_in[11];
    const float* cls_bb = (const float*)d_in[12];
    const float* cls_m  = (const float*)d_in[13];
    const float* cls_v  = (const float*)d_in[14];
    const float* cls_w2 = (const float*)d_in[15];
    const float* cls_b2 = (const float*)d_in[16];
    const float* tok_w  = (const float*)d_in[17];
    const float* tok_b  = (const float*)d_in[18];
    const float* emb    = (const float*)d_in[19];
    const float* ln1_g  = (const float*)d_in[20];
    const float* ln1_b  = (const float*)d_in[21];
    const float* qkv_w  = (const float*)d_in[22];
    const float* out_w  = (const float*)d_in[23];
    const float* out_b  = (const float*)d_in[24];
    const float* ln2_g  = (const float*)d_in[25];
    const float* ln2_b  = (const float*)d_in[26];
    const float* ff_w1  = (const float*)d_in[27];
    const float* ff_b1  = (const float*)d_in[28];
    const float* ff_w2  = (const float*)d_in[29];
    const float* ff_b2  = (const float*)d_in[30];
    const float* lnf_g  = (const float*)d_in[31];
    const float* lnf_b  = (const float*)d_in[32];
    const float* fin_w  = (const float*)d_in[33];
    const float* fin_b  = (const float*)d_in[34];

    float* out = (float*)d_out;
    float* ws  = (float*)d_ws;

    // workspace layout (float offsets)
    float*  Wc32     = ws;                        // 184320
    float*  cconst   = ws + 184320;               // 160
    ushort* Wchi     = (ushort*)(ws + 184480);    // 184320 ushorts (92160 floats)
    ushort* Wclo     = (ushort*)(ws + 276640);    // 92160 floats
    float*  logitsP  = ws + 368800;               // 3*18432*160 = 8847360
    float*  partials = ws + 9216160;              // 4608
    float*  patches  = ws + 9220768;              // 737280
    float*  z2_5     = ws + 9958048;              // 32768
    float*  t5buf    = ws + 9990816;              // 32768
    float*  f5buf    = ws + 10023584;             // 65536
    float*  tfin     = ws + 10089120;             // 32768
    float*  refined5 = ws + 10121888;             // 737280
    float*  tpart    = ws + 10859168;             // 262144
    int*    amax     = (int*)(ws + 11121312);     // 18432
    int*    flag     = (int*)(ws + 11139744);     // 1
    int*    cand_cnt = (int*)(ws + 11139745);     // 1
    int*    cand_lst = (int*)(ws + 11139746);     // 18432
    float*  w1cT     = ws + 11158180;             // 294912
    float*  w2cT     = ws + 11453092;             // 36864
    float*  WcT      = ws + 11489956;             // 1152*160 = 184320 -> ends 11674276

    // output offsets: ext | cls | ext2 | cls2
    float* out_ext  = out;
    float* out_cls  = out + 36864;
    float* out_ext2 = out + 2691072;
    float* out_cls2 = out + 2727936;

    dim3 blk(256);

    // combined weights + transposed weights (independent of x)
    wcomb_build<<<160, blk, 0, stream>>>(
        ext_w1, ext_b1, ext_g, ext_bb, ext_m, ext_v, ext_w2, ext_b2,
        cls_w1, cls_b1, cls_g, cls_bb, cls_m, cls_v, cls_w2, cls_b2,
        Wc32, Wchi, Wclo, cconst);
    zero_counters<<<1, 1, 0, stream>>>(cand_cnt);
    transpose_w<<<dim3(36, 8), blk, 0, stream>>>(cls_w1, w1cT, 256, 1152);
    transpose_w<<<dim3(8, 5), blk, 0, stream>>>(cls_w2, w2cT, 144, 256);
    transpose_w<<<dim3(36, 5), blk, 0, stream>>>(Wc32, WcT, 160, 1152);

    // pass 1
    logits_gemm<<<dim3(288, NKS), blk, 0, stream>>>(x, Wchi, Wclo, logitsP);
    softmax_heads<<<4608, blk, 0, stream>>>(logitsP, cconst, out_cls, out_ext, amax, partials,
        cand_cnt, cand_lst);
    reduce_flag<<<1, blk, 0, stream>>>(partials, 4608, flag);
    fixup_list<<<256, blk, 0, stream>>>(cand_cnt, cand_lst, x,
        w1cT, cls_b1, cls_g, cls_bb, cls_m, cls_v, w2cT, cls_b2, amax);

    // refine chain (always computed; application predicated on flag)
    gather_patches<<<2880, blk, 0, stream>>>(x, amax, patches);
    tok_partial<<<dim3(128, 8), blk, 0, stream>>>(patches, tok_w, tpart);
    attn_front<<<128, dim3(512), 0, stream>>>(tpart, tok_b, emb, ln1_g, ln1_b, qkv_w,
        out_w, out_b, ln2_g, ln2_b, z2_5, t5buf);
    ff1_gelu<<<dim3(128, 2), blk, 0, stream>>>(z2_5, ff_w1, ff_b1, f5buf);
    ff2_lnf<<<128, blk, 0, stream>>>(f5buf, ff_w2, ff_b2, t5buf, lnf_g, lnf_b, tfin);
    fin_gemm<<<dim3(23, 8), blk, 0, stream>>>(tfin, fin_w, fin_b, refined5);

    // pass 2 = pass 1 logits + rank-40 per-row delta (no second GEMM)
    delta_logits<<<4608, blk, 0, stream>>>(x, WcT, amax, refined5, flag, logitsP);
    softmax_heads<<<4608, blk, 0, stream>>>(logitsP, cconst, out_cls2, out_ext2, nullptr, nullptr,
        nullptr, nullptr);
}

// Round 11
// 344.344 us; speedup vs baseline: 1.5042x; 1.0711x over previous
//
#include <hip/hip_runtime.h>
#include <math.h>

#define EPSF 1e-5f
#define GAPTH 1e-3f
#define NKS 4           // K-split slices for logits GEMM (288 each)
#define KSL 288
#define RROWS 18432

// B=128, C=8, H=144, W=144, CW=1152, R=18432, TW=5, OG=2, NCLS=6, DT=256, ITC=5760
// Collapsed head: logits[row, j] = sum_k Wc[j,k] * x'[row,k] + cconst[j]
//   j 0..143 = cls, j 144..145 = ext, j 146..159 = zero pad. NP=160.
// Pass 2 = pass 1 + rank-40 per-row delta, fused into softmax (DELTA=1).

typedef __attribute__((ext_vector_type(8))) short short8v;
typedef __attribute__((ext_vector_type(4))) float f32x4;
typedef unsigned short ushort;
typedef unsigned int uint;

__device__ inline ushort f2bf(float f) {
    uint u = __float_as_uint(f);
    uint r = (u + 0x7FFFu + ((u >> 16) & 1u)) >> 16;
    return (ushort)r;
}
__device__ inline float bf2f(ushort h) { return __uint_as_float(((uint)h) << 16); }

// ---------------------------------------------------------------------------
// Build combined weights, K-split over blockIdx.y for occupancy.
// Wc[j,k] = sum_o w2[j,o]*s[o]*w1[o,k]; cconst[j] = affine const + b2[j].
// ---------------------------------------------------------------------------
__global__ __launch_bounds__(256) void wcomb_build(
    const float* __restrict__ w1e, const float* __restrict__ b1e, const float* __restrict__ ge,
    const float* __restrict__ bbe, const float* __restrict__ me, const float* __restrict__ ve,
    const float* __restrict__ w2e, const float* __restrict__ b2e,
    const float* __restrict__ w1c, const float* __restrict__ b1c, const float* __restrict__ gc,
    const float* __restrict__ bbc, const float* __restrict__ mc, const float* __restrict__ vc,
    const float* __restrict__ w2c, const float* __restrict__ b2c,
    float* __restrict__ Wc32, ushort* __restrict__ Wchi, ushort* __restrict__ Wclo,
    float* __restrict__ cconst)
{
    __shared__ float coef[256];
    __shared__ float csum[4];
    const int j = blockIdx.x, kq = blockIdx.y, tid = threadIdx.x;
    const int lane = tid & 63, wid = tid >> 6;

    const float *w1 = nullptr, *w2row = nullptr, *b1 = nullptr, *g = nullptr,
                *bb = nullptr, *m = nullptr, *v = nullptr;
    float b2v = 0.f;
    int valid = 0;
    if (j < 144) {
        valid = 1; w1 = w1c; w2row = w2c + (size_t)j * 256;
        b1 = b1c; g = gc; bb = bbc; m = mc; v = vc; b2v = b2c[j];
    } else if (j < 146) {
        valid = 1; w1 = w1e; w2row = w2e + (size_t)(j - 144) * 256;
        b1 = b1e; g = ge; bb = bbe; m = me; v = ve; b2v = b2e[j - 144];
    }

    float cf = 0.f, cc = 0.f;
    if (valid) {
        float s = g[tid] * rsqrtf(v[tid] + EPSF);
        float w2v = w2row[tid];
        cf = w2v * s;
        cc = w2v * ((b1[tid] - m[tid]) * s + bb[tid]);
    }
    coef[tid] = cf;
    if (kq == 0) {
        float t = cc;
#pragma unroll
        for (int off = 32; off; off >>= 1) t += __shfl_xor(t, off);
        if (lane == 0) csum[wid] = t;
    }
    __syncthreads();
    if (kq == 0 && tid == 0)
        cconst[j] = valid ? ((csum[0] + csum[1]) + (csum[2] + csum[3]) + b2v) : 0.f;

    for (int k = kq * KSL + tid; k < (kq + 1) * KSL; k += 256) {
        float acc = 0.f;
        if (valid) {
            for (int o = 0; o < 256; o++) acc += coef[o] * w1[(size_t)o * 1152 + k];
        }
        Wc32[(size_t)j * 1152 + k] = acc;
        ushort hi = f2bf(acc);
        Wchi[(size_t)j * 1152 + k] = hi;
        Wclo[(size_t)j * 1152 + k] = f2bf(acc - bf2f(hi));
    }
}

__global__ void zero_counters(int* __restrict__ cand_count)
{
    *cand_count = 0;
}

// ---------------------------------------------------------------------------
// tiled transpose: src[R][Cc] -> dst[Cc][R]
// ---------------------------------------------------------------------------
__global__ __launch_bounds__(256) void transpose_w(
    const float* __restrict__ src, float* __restrict__ dst, int R, int Cc)
{
    __shared__ float tile[32][33];
    const int rb = blockIdx.y * 32, cb = blockIdx.x * 32;
    const int tx = threadIdx.x & 31, ty = threadIdx.x >> 5;
#pragma unroll
    for (int i = ty; i < 32; i += 8) {
        int r = rb + i, c = cb + tx;
        tile[i][tx] = (r < R && c < Cc) ? src[(size_t)r * Cc + c] : 0.f;
    }
    __syncthreads();
#pragma unroll
    for (int i = ty; i < 32; i += 8) {
        int c = cb + i, r = rb + tx;
        if (c < Cc && r < R) dst[(size_t)c * R + r] = tile[tx][i];
    }
}

// ---------------------------------------------------------------------------
// logits GEMM: M=18432, N=160(146 used), K=1152 in NKS=4 slices of 288.
// BM=128, BN=160, BK=32; 4 waves as 2m x 2n; wave tile 64x80 (4x5 frags).
// Split-bf16 MFMA (hi/lo, 3 products). Writes per-slice partials.
// ---------------------------------------------------------------------------
__global__ __launch_bounds__(256) void logits_gemm(
    const float* __restrict__ x, const ushort* __restrict__ Wchi, const ushort* __restrict__ Wclo,
    float* __restrict__ logits_part)
{
    __shared__ ushort Ahi[128][40], Alo[128][40], Bhi[160][40], Blo[160][40];
    const int tid = threadIdx.x;
    const int lane = tid & 63, wid = tid >> 6;
    const int wm = wid & 1, wn = wid >> 1;
    const int rb = blockIdx.x * 128;
    const int ks = blockIdx.y;
    const int kbase = ks * KSL;
    const int NIT = KSL / 32;                    // 9

    // A staging: thread t loads row t>>1, 16 contiguous k at (t&1)*16
    const int rl = tid >> 1, kq = (tid & 1) << 4;
    const int arow = rb + rl;
    const int ab = arow / 144, ahh = arow - ab * 144;

    // B staging: rows 0..127 same mapping; rows 128..159 by tid<64
    const int br2 = 128 + (tid >> 1);

    float av[16];
    short8v vb0a, vb0b, vl0a, vl0b;   // B rows 0..127 (16 ushorts hi + 16 lo)
    short8v vb2a, vb2b, vl2a, vl2b;   // B rows 128..159 (tid<64)

    auto LOAD = [&](int kb) {
        const int k0 = kb + kq;                      // multiple of 16
        const int c = k0 / 144, w = k0 - c * 144;    // 16-chunk never crosses c (144%16==0)
        const float* xp = x + (((size_t)(ab * 8 + c) * 144 + ahh) * 144 + w);
#pragma unroll
        for (int q = 0; q < 4; q++) {
            const float4 t4 = *reinterpret_cast<const float4*>(xp + q * 4);
            av[q * 4 + 0] = t4.x; av[q * 4 + 1] = t4.y;
            av[q * 4 + 2] = t4.z; av[q * 4 + 3] = t4.w;
        }
        const ushort* bh = Wchi + (size_t)rl * 1152 + k0;
        const ushort* bl = Wclo + (size_t)rl * 1152 + k0;
        vb0a = *reinterpret_cast<const short8v*>(bh);
        vb0b = *reinterpret_cast<const short8v*>(bh + 8);
        vl0a = *reinterpret_cast<const short8v*>(bl);
        vl0b = *reinterpret_cast<const short8v*>(bl + 8);
        if (tid < 64) {
            const ushort* bh2 = Wchi + (size_t)br2 * 1152 + k0;
            const ushort* bl2 = Wclo + (size_t)br2 * 1152 + k0;
            vb2a = *reinterpret_cast<const short8v*>(bh2);
            vb2b = *reinterpret_cast<const short8v*>(bh2 + 8);
            vl2a = *reinterpret_cast<const short8v*>(bl2);
            vl2b = *reinterpret_cast<const short8v*>(bl2 + 8);
        }
    };

    auto STORE = [&]() {
        short8v hv0, hv1, lv0, lv1;
#pragma unroll
        for (int q = 0; q < 8; q++) {
            ushort h = f2bf(av[q]);
            hv0[q] = (short)h; lv0[q] = (short)f2bf(av[q] - bf2f(h));
        }
#pragma unroll
        for (int q = 0; q < 8; q++) {
            ushort h = f2bf(av[8 + q]);
            hv1[q] = (short)h; lv1[q] = (short)f2bf(av[8 + q] - bf2f(h));
        }
        *reinterpret_cast<short8v*>(&Ahi[rl][kq]) = hv0;
        *reinterpret_cast<short8v*>(&Ahi[rl][kq + 8]) = hv1;
        *reinterpret_cast<short8v*>(&Alo[rl][kq]) = lv0;
        *reinterpret_cast<short8v*>(&Alo[rl][kq + 8]) = lv1;
        *reinterpret_cast<short8v*>(&Bhi[rl][kq]) = vb0a;
        *reinterpret_cast<short8v*>(&Bhi[rl][kq + 8]) = vb0b;
        *reinterpret_cast<short8v*>(&Blo[rl][kq]) = vl0a;
        *reinterpret_cast<short8v*>(&Blo[rl][kq + 8]) = vl0b;
        if (tid < 64) {
            *reinterpret_cast<short8v*>(&Bhi[br2][kq]) = vb2a;
            *reinterpret_cast<short8v*>(&Bhi[br2][kq + 8]) = vb2b;
            *reinterpret_cast<short8v*>(&Blo[br2][kq]) = vl2a;
            *reinterpret_cast<short8v*>(&Blo[br2][kq + 8]) = vl2b;
        }
    };

    f32x4 acc[4][5];
#pragma unroll
    for (int mt = 0; mt < 4; mt++)
#pragma unroll
        for (int nt = 0; nt < 5; nt++) acc[mt][nt] = (f32x4){0.f, 0.f, 0.f, 0.f};

    const int fr = lane & 15, fg = (lane >> 4) << 3;

    LOAD(kbase);
    for (int t = 0; t < NIT; t++) {
        STORE();
        if (t < NIT - 1) LOAD(kbase + (t + 1) * 32);
        __syncthreads();
        short8v ah[4], al[4];
#pragma unroll
        for (int mt = 0; mt < 4; mt++) {
            ah[mt] = *reinterpret_cast<const short8v*>(&Ahi[wm * 64 + mt * 16 + fr][fg]);
            al[mt] = *reinterpret_cast<const short8v*>(&Alo[wm * 64 + mt * 16 + fr][fg]);
        }
#pragma unroll
        for (int nt = 0; nt < 5; nt++) {
            short8v bh = *reinterpret_cast<const short8v*>(&Bhi[wn * 80 + nt * 16 + fr][fg]);
            short8v bl = *reinterpret_cast<const short8v*>(&Blo[wn * 80 + nt * 16 + fr][fg]);
#pragma unroll
            for (int mt = 0; mt < 4; mt++) {
                acc[mt][nt] = __builtin_amdgcn_mfma_f32_16x16x32_bf16(ah[mt], bh, acc[mt][nt], 0, 0, 0);
                acc[mt][nt] = __builtin_amdgcn_mfma_f32_16x16x32_bf16(ah[mt], bl, acc[mt][nt], 0, 0, 0);
                acc[mt][nt] = __builtin_amdgcn_mfma_f32_16x16x32_bf16(al[mt], bh, acc[mt][nt], 0, 0, 0);
            }
        }
        __syncthreads();
    }

    // epilogue: C/D layout col=lane&15, row=(lane>>4)*4+i  [m89-verified]
    float* base = logits_part + (size_t)ks * RROWS * 160;
#pragma unroll
    for (int mt = 0; mt < 4; mt++) {
#pragma unroll
        for (int nt = 0; nt < 5; nt++) {
            int gcol = wn * 80 + nt * 16 + fr;
            if (gcol < 146) {
                float* dst = base + (size_t)(rb + wm * 64 + mt * 16 + ((lane >> 4) << 2)) * 160 + gcol;
#pragma unroll
                for (int i = 0; i < 4; i++)
                    dst[(size_t)i * 160] = acc[mt][nt][i];
            }
        }
    }
}

// ---------------------------------------------------------------------------
// merged softmax over summed K-slices. DELTA=1 (pass 2): add rank-40 per-row
// patch delta (exact f32) inline before softmax; no-op when *flag==0.
// cls cols 0..143 (+argmax & gap->cands in pass 1), ext cols 144..145.
// One wave per row, 4 rows per block.
// ---------------------------------------------------------------------------
template<int DELTA>
__global__ __launch_bounds__(256) void softmax_heads(
    const float* __restrict__ logits_part, const float* __restrict__ cconst,
    float* __restrict__ out_cls, float* __restrict__ out_ext,
    int* __restrict__ amax, float* __restrict__ partials,
    int* __restrict__ cand_count, int* __restrict__ cand_list,
    const float* __restrict__ x, const float* __restrict__ WcT,
    const float* __restrict__ refined5, const int* __restrict__ flag)
{
    __shared__ float ps[4];
    __shared__ float dL[4][148];
    __shared__ float dsh[4][40];
    __shared__ int   ksh[4][40];
    const int r4 = threadIdx.x >> 6, lane = threadIdx.x & 63;
    const int row = blockIdx.x * 4 + r4;

    if (DELTA) {
        const int fl = *flag;
        if (fl) {
            const int b = row / 144, hh = row - b * 144;
            const int a = amax[row];
            if (lane < 40) {
                int c = lane / 5, tw = lane - c * 5;
                int w = a - 2 + tw;
                float d = 0.f; int k = 0;
                if (w >= 0 && w < 144) {
                    k = c * 144 + w;
                    d = refined5[(size_t)b * 5760 + (c * 144 + hh) * 5 + tw]
                      - x[((size_t)(b * 8 + c) * 144 + hh) * 144 + w];
                }
                dsh[r4][lane] = d; ksh[r4][lane] = k;
            }
            __syncthreads();
#pragma unroll
            for (int rj = 0; rj < 3; rj++) {
                int j = lane + rj * 64;
                if (j < 146) {
                    float acc = 0.f;
#pragma unroll 8
                    for (int i = 0; i < 40; i++)
                        acc += WcT[(size_t)ksh[r4][i] * 160 + j] * dsh[r4][i];
                    dL[r4][j] = acc;
                }
            }
        } else {
#pragma unroll
            for (int rj = 0; rj < 3; rj++) {
                int j = lane + rj * 64;
                if (j < 146) dL[r4][j] = 0.f;
            }
        }
        __syncthreads();
    }

    const float* L0 = logits_part + (size_t)row * 160;
    const float* L1 = L0 + (size_t)RROWS * 160;
    const float* L2 = L1 + (size_t)RROWS * 160;
    const float* L3 = L2 + (size_t)RROWS * 160;
    float v0 = L0[lane] + L1[lane] + L2[lane] + L3[lane] + cconst[lane];
    float v1 = L0[lane + 64] + L1[lane + 64] + L2[lane + 64] + L3[lane + 64] + cconst[lane + 64];
    float v2 = (lane < 16) ? (L0[lane + 128] + L1[lane + 128] + L2[lane + 128] + L3[lane + 128]
                              + cconst[lane + 128])
                           : -3.0e38f;
    if (DELTA) {
        v0 += dL[r4][lane];
        v1 += dL[r4][lane + 64];
        if (lane < 16) v2 += dL[r4][lane + 128];
    }
    // argmax (first-max tie rule) + top-2 values
    float m = v0; int mi = lane;
    if (v1 > m) { m = v1; mi = lane + 64; }
    if (v2 > m) { m = v2; mi = lane + 128; }
    float m1 = v0, m2 = -3.0e38f;
    if (v1 > m1) { m2 = m1; m1 = v1; } else m2 = v1;
    if (v2 > m1) { m2 = m1; m1 = v2; } else m2 = fmaxf(m2, v2);
#pragma unroll
    for (int off = 32; off; off >>= 1) {
        float om = __shfl_xor(m, off);
        int   oi = __shfl_xor(mi, off);
        if (om > m || (om == m && oi < mi)) { m = om; mi = oi; }
        float om1 = __shfl_xor(m1, off);
        float om2 = __shfl_xor(m2, off);
        float nm1 = fmaxf(m1, om1);
        m2 = fmaxf(fminf(m1, om1), fmaxf(m2, om2));
        m1 = nm1;
    }
    float e0 = expf(v0 - m), e1 = expf(v1 - m);
    float e2 = (lane < 16) ? expf(v2 - m) : 0.f;
    float s = e0 + e1 + e2;
#pragma unroll
    for (int off = 32; off; off >>= 1) s += __shfl_xor(s, off);
    float inv = 1.f / s;
    float* O = out_cls + (size_t)row * 144;
    O[lane] = e0 * inv;
    O[lane + 64] = e1 * inv;
    if (lane < 16) O[lane + 128] = e2 * inv;

    // ext head (2 logits)
    float l0 = L0[144] + L1[144] + L2[144] + L3[144] + cconst[144];
    float l1 = L0[145] + L1[145] + L2[145] + L3[145] + cconst[145];
    if (DELTA) { l0 += dL[r4][144]; l1 += dL[r4][145]; }
    float mx = fmaxf(l0, l1);
    float ee0 = expf(l0 - mx), ee1 = expf(l1 - mx);
    float einv = 1.f / (ee0 + ee1);
    float p0 = ee0 * einv;
    if (lane == 0) {
        out_ext[(size_t)row * 2] = p0;
        out_ext[(size_t)row * 2 + 1] = ee1 * einv;
        if (amax != nullptr && !DELTA) {
            amax[row] = mi;
            if (m1 - m2 < GAPTH) {
                int slot = atomicAdd(cand_count, 1);
                cand_list[slot] = row;
            }
        }
    }
    if (partials != nullptr) {
        if (lane == 0) ps[r4] = p0;
        __syncthreads();
        if (threadIdx.x == 0) partials[blockIdx.x] = (ps[0] + ps[1]) + (ps[2] + ps[3]);
    }
}

__global__ __launch_bounds__(256) void reduce_flag(const float* __restrict__ partials, int n,
                                                   int* __restrict__ flag)
{
    __shared__ float sm[256];
    int tid = threadIdx.x;
    float s = 0.f;
    for (int i = tid; i < n; i += 256) s += partials[i];
    sm[tid] = s; __syncthreads();
    for (int off = 128; off; off >>= 1) {
        if (tid < off) sm[tid] += sm[tid + off];
        __syncthreads();
    }
    if (tid == 0) *flag = (sm[0] * (1.f / 18432.f) > 0.3f) ? 1 : 0;
}

// ---------------------------------------------------------------------------
// fixup over compacted candidate list: exact f32 two-stage recompute of argmax.
// ---------------------------------------------------------------------------
__global__ __launch_bounds__(256) void fixup_list(
    const int* __restrict__ cand_count, const int* __restrict__ cand_list,
    const float* __restrict__ x,
    const float* __restrict__ w1cT, const float* __restrict__ b1c,
    const float* __restrict__ gc, const float* __restrict__ bbc,
    const float* __restrict__ mc, const float* __restrict__ vc,
    const float* __restrict__ w2cT, const float* __restrict__ b2c,
    int* __restrict__ amax)
{
    __shared__ float xrow[1152];
    __shared__ float hsh[256];
    __shared__ float Lsh[144];
    const int tid = threadIdx.x;
    const int n = *cand_count;

    for (int ci = blockIdx.x; ci < n; ci += gridDim.x) {
        const int row = cand_list[ci];
        const int b = row / 144, hh = row - b * 144;
        for (int e = tid; e < 1152; e += 256) {
            int c = e / 144, w = e - c * 144;
            xrow[e] = x[(((size_t)(b * 8 + c) * 144 + hh) * 144) + w];
        }
        __syncthreads();
        {
            float a = 0.f;
#pragma unroll 8
            for (int k = 0; k < 1152; k++) a += w1cT[(size_t)k * 256 + tid] * xrow[k];
            float sc = gc[tid] * rsqrtf(vc[tid] + EPSF);
            hsh[tid] = (a + b1c[tid] - mc[tid]) * sc + bbc[tid];
        }
        __syncthreads();
        if (tid < 144) {
            float a = 0.f;
#pragma unroll 8
            for (int k = 0; k < 256; k++) a += w2cT[(size_t)k * 144 + tid] * hsh[k];
            Lsh[tid] = a + b2c[tid];
        }
        __syncthreads();
        if (tid == 0) {
            int bi = 0; float bv = Lsh[0];
            for (int j = 1; j < 144; j++) if (Lsh[j] > bv) { bv = Lsh[j]; bi = j; }
            amax[row] = bi;
        }
        __syncthreads();
    }
}

// ---------------------------------------------------------------------------
// tok GEMM with fused patch gather. Block (b, ks=c): P[720] gathered from
// xpad[b,c,hh,amax(hh)+tw-2] directly (5760 = 8 channels x 720; ks == c).
// ---------------------------------------------------------------------------
__global__ __launch_bounds__(256) void tok_partial(const float* __restrict__ x,
    const int* __restrict__ amax, const float* __restrict__ tok_w, float* __restrict__ tpart)
{
    __shared__ float P[720];
    __shared__ int ash[144];
    int b = blockIdx.x, c = blockIdx.y, tid = threadIdx.x;
    if (tid < 144) ash[tid] = amax[b * 144 + tid];
    __syncthreads();
    for (int e = tid; e < 720; e += 256) {
        int hh = e / 5, tw = e - hh * 5;
        int w = ash[hh] + tw - 2;
        P[e] = (w >= 0 && w < 144) ? x[(((size_t)(b * 8 + c) * 144 + hh) * 144) + w] : 0.f;
    }
    __syncthreads();
    float acc = 0.f;
    const float* wbase = tok_w + (size_t)c * 720 * 256;
    for (int k = 0; k < 720; k++) acc += P[k] * wbase[(size_t)k * 256 + tid];
    tpart[((size_t)b * 8 + c) * 256 + tid] = acc;
}

// ---------------------------------------------------------------------------
// attn_front: tok_finish + LN1(x6) + qkv (q only for token 5) + attention row 5
// + out-proj token 5 + residual + LN2.  One block per batch elem, 512 threads.
// ---------------------------------------------------------------------------
__global__ __launch_bounds__(512) void attn_front(
    const float* __restrict__ tpart, const float* __restrict__ tok_b,
    const float* __restrict__ emb,
    const float* __restrict__ ln1_g, const float* __restrict__ ln1_b,
    const float* __restrict__ qkv_w,
    const float* __restrict__ out_w, const float* __restrict__ out_b,
    const float* __restrict__ ln2_g, const float* __restrict__ ln2_b,
    float* __restrict__ z2_5, float* __restrict__ t5out)
{
    __shared__ float s[256];
    __shared__ float z[6][256];
    __shared__ float qk[6][192];
    __shared__ float att[2][6];
    __shared__ float o5[64];
    __shared__ float t5[256];
    __shared__ float stat[2];
    const int b = blockIdx.x, tid = threadIdx.x;
    const int lane = tid & 63, wv = tid >> 6;

    if (tid < 256) {
        float a = tok_b[tid];
        for (int ks = 0; ks < 8; ks++) a += tpart[((size_t)b * 8 + ks) * 256 + tid];
        s[tid] = a;
    }
    __syncthreads();

    if (wv < 6) {
        float y[4], s1 = 0.f, s2 = 0.f;
#pragma unroll
        for (int q = 0; q < 4; q++) {
            int k = lane + 64 * q;
            y[q] = s[k] + emb[wv * 256 + k];
            s1 += y[q]; s2 += y[q] * y[q];
        }
#pragma unroll
        for (int off = 32; off; off >>= 1) { s1 += __shfl_xor(s1, off); s2 += __shfl_xor(s2, off); }
        float mu = s1 * (1.f / 256.f);
        float var = s2 * (1.f / 256.f) - mu * mu;
        float rs = rsqrtf(var + EPSF);
#pragma unroll
        for (int q = 0; q < 4; q++) {
            int k = lane + 64 * q;
            z[wv][k] = (y[q] - mu) * rs * ln1_g[k] + ln1_b[k];
        }
    }
    __syncthreads();

    for (int d = tid; d < 832; d += 512) {
        int i, c;
        if (d < 768) { i = d >> 7; c = 64 + (d & 127); }
        else         { i = 5;      c = d - 768; }
        float a = 0.f;
#pragma unroll 4
        for (int k = 0; k < 256; k++) a += z[i][k] * qkv_w[(size_t)k * 192 + c];
        qk[i][c] = a;
    }
    __syncthreads();

    if (tid < 12) {
        int h = tid / 6, j = tid - h * 6;
        float a = 0.f;
#pragma unroll
        for (int d = 0; d < 32; d++) a += qk[5][h * 32 + d] * qk[j][64 + h * 32 + d];
        att[h][j] = a * 0.17677669529663687f;
    }
    __syncthreads();
    if (tid < 2) {
        float m = -3.0e38f;
        for (int j = 0; j < 6; j++) m = fmaxf(m, att[tid][j]);
        float ssum = 0.f;
        for (int j = 0; j < 6; j++) { float e = expf(att[tid][j] - m); att[tid][j] = e; ssum += e; }
        float inv = 1.f / ssum;
        for (int j = 0; j < 6; j++) att[tid][j] *= inv;
    }
    __syncthreads();
    if (tid < 64) {
        int h = tid >> 5;
        float a = 0.f;
#pragma unroll
        for (int j = 0; j < 6; j++) a += att[h][j] * qk[j][128 + tid];
        o5[tid] = a;
    }
    __syncthreads();

    if (tid < 256) {
        float a = out_b[tid] + s[tid] + emb[5 * 256 + tid];
#pragma unroll 4
        for (int d = 0; d < 64; d++) a += o5[d] * out_w[(size_t)d * 256 + tid];
        t5[tid] = a;
    }
    __syncthreads();

    if (wv == 0) {
        float s1 = 0.f, s2 = 0.f;
#pragma unroll
        for (int q = 0; q < 4; q++) { float vv = t5[lane + 64 * q]; s1 += vv; s2 += vv * vv; }
#pragma unroll
        for (int off = 32; off; off >>= 1) { s1 += __shfl_xor(s1, off); s2 += __shfl_xor(s2, off); }
        if (lane == 0) {
            float mu = s1 * (1.f / 256.f);
            float var = s2 * (1.f / 256.f) - mu * mu;
            stat[0] = mu; stat[1] = rsqrtf(var + EPSF);
        }
    }
    __syncthreads();
    if (tid < 256) {
        t5out[(size_t)b * 256 + tid] = t5[tid];
        z2_5[(size_t)b * 256 + tid] = (t5[tid] - stat[0]) * stat[1] * ln2_g[tid] + ln2_b[tid];
    }
}

// ---------------------------------------------------------------------------
// ff1 + exact gelu for token 5
// ---------------------------------------------------------------------------
__global__ __launch_bounds__(256) void ff1_gelu(
    const float* __restrict__ z2_5, const float* __restrict__ ff_w1,
    const float* __restrict__ ff_b1, float* __restrict__ f5)
{
    __shared__ float zsh[256];
    const int b = blockIdx.x, half = blockIdx.y, tid = threadIdx.x;
    zsh[tid] = z2_5[(size_t)b * 256 + tid];
    __syncthreads();
    const int jj = half * 256 + tid;
    float a = ff_b1[jj];
#pragma unroll 4
    for (int k = 0; k < 256; k++) a += zsh[k] * ff_w1[(size_t)k * 512 + jj];
    f5[(size_t)b * 512 + jj] = 0.5f * a * (1.f + erff(a * 0.70710678118654752f));
}

// ---------------------------------------------------------------------------
// ff2 + residual + LNF for token 5 -> tfin
// ---------------------------------------------------------------------------
__global__ __launch_bounds__(256) void ff2_lnf(
    const float* __restrict__ f5, const float* __restrict__ ff_w2,
    const float* __restrict__ ff_b2, const float* __restrict__ t5in,
    const float* __restrict__ lnf_g, const float* __restrict__ lnf_b,
    float* __restrict__ tfin)
{
    __shared__ float fsh[512];
    __shared__ float tsh[256];
    __shared__ float stat[2];
    const int b = blockIdx.x, tid = threadIdx.x;
    const int lane = tid & 63;
    fsh[tid] = f5[(size_t)b * 512 + tid];
    fsh[tid + 256] = f5[(size_t)b * 512 + tid + 256];
    __syncthreads();
    float a = ff_b2[tid] + t5in[(size_t)b * 256 + tid];
#pragma unroll 4
    for (int k = 0; k < 512; k++) a += fsh[k] * ff_w2[(size_t)k * 256 + tid];
    tsh[tid] = a;
    __syncthreads();
    if (tid < 64) {
        float s1 = 0.f, s2 = 0.f;
#pragma unroll
        for (int q = 0; q < 4; q++) { float vv = tsh[lane + 64 * q]; s1 += vv; s2 += vv * vv; }
#pragma unroll
        for (int off = 32; off; off >>= 1) { s1 += __shfl_xor(s1, off); s2 += __shfl_xor(s2, off); }
        if (lane == 0) {
            float mu = s1 * (1.f / 256.f);
            float var = s2 * (1.f / 256.f) - mu * mu;
            stat[0] = mu; stat[1] = rsqrtf(var + EPSF);
        }
    }
    __syncthreads();
    tfin[(size_t)b * 256 + tid] = (tsh[tid] - stat[0]) * stat[1] * lnf_g[tid] + lnf_b[tid];
}

// ---------------------------------------------------------------------------
// fin GEMM for token 5: refined5[b,n] = tfin[b,:] @ fin_w[:,n] + fin_b[n]
// ---------------------------------------------------------------------------
__global__ __launch_bounds__(256) void fin_gemm(const float* __restrict__ tfin,
    const float* __restrict__ fin_w, const float* __restrict__ fin_b, float* __restrict__ refined5)
{
    __shared__ float tf[16][256];
    int tid = threadIdx.x;
    int nb = blockIdx.x * 256 + tid;
    int bg = blockIdx.y * 16;
    for (int e = tid; e < 4096; e += 256) tf[e >> 8][e & 255] = tfin[(size_t)(bg + (e >> 8)) * 256 + (e & 255)];
    __syncthreads();
    if (nb < 5760) {
        float acc[16];
#pragma unroll
        for (int bb = 0; bb < 16; bb++) acc[bb] = 0.f;
        for (int k = 0; k < 256; k++) {
            float wv = fin_w[(size_t)k * 5760 + nb];
#pragma unroll
            for (int bb = 0; bb < 16; bb++) acc[bb] += tf[bb][k] * wv;
        }
        float fb = fin_b[nb];
#pragma unroll
        for (int bb = 0; bb < 16; bb++)
            refined5[(size_t)(bg + bb) * 5760 + nb] = acc[bb] + fb;
    }
}

// ---------------------------------------------------------------------------
extern "C" void kernel_launch(void* const* d_in, const int* in_sizes, int n_in,
                              void* d_out, int out_size, void* d_ws, size_t ws_size,
                              hipStream_t stream)
{
    const float* x      = (const float*)d_in[0];
    const float* ext_w1 = (const float*)d_in[1];
    const float* ext_b1 = (const float*)d_in[2];
    const float* ext_g  = (const float*)d_in[3];
    const float* ext_bb = (const float*)d_in[4];
    const float* ext_m  = (const float*)d_in[5];
    const float* ext_v  = (const float*)d_in[6];
    const float* ext_w2 = (const float*)d_in[7];
    const float* ext_b2 = (const float*)d_in[8];
    const float* cls_w1 = (const float*)d_in[9];
    const float* cls_b1 = (const float*)d_in[10];
    const float* cls_g  = (const float*)d_in[11];
    const float* cls_bb = (const float*)d_in[12];
    const float* cls_m  = (const float*)d_in[13];
    const float* cls_v  = (const float*)d_in[14];
    const float* cls_w2 = (const float*)d_in[15];
    const float* cls_b2 = (const float*)d_in[16];
    const float* tok_w  = (const float*)d_in[17];
    const float* tok_b  = (const float*)d_in[18];
    const float* emb    = (const float*)d_in[19];
    const float* ln1_g  = (const float*)d_in[20];
    const float* ln1_b  = (const float*)d_in[21];
    const float* qkv_w  = (const float*)d_in[22];
    const float* out_w  = (const float*)d_in[23];
    const float* out_b  = (const float*)d_in[24];
    const float* ln2_g  = (const float*)d_in[25];
    const float* ln2_b  = (const float*)d_in[26];
    const float* ff_w1  = (const float*)d_in[27];
    const float* ff_b1  = (const float*)d_in[28];
    const float* ff_w2  = (const float*)d_in[29];
    const float* ff_b2  = (const float*)d_in[30];
    const float* lnf_g  = (const float*)d_in[31];
    const float* lnf_b  = (const float*)d_in[32];
    const float* fin_w  = (const float*)d_in[33];
    const float* fin_b  = (const float*)d_in[34];

    float* out = (float*)d_out;
    float* ws  = (float*)d_ws;

    // workspace layout (float offsets)
    float*  Wc32     = ws;                        // 184320
    float*  cconst   = ws + 184320;               // 160
    ushort* Wchi     = (ushort*)(ws + 184480);    // 92160 floats
    ushort* Wclo     = (ushort*)(ws + 276640);    // 92160 floats
    float*  logitsP  = ws + 368800;               // 4*18432*160 = 11796480
    float*  partials = ws + 12165280;             // 4608
    float*  z2_5     = ws + 12169888;             // 32768
    float*  t5buf    = ws + 12202656;             // 32768
    float*  f5buf    = ws + 12235424;             // 65536
    float*  tfin     = ws + 12300960;             // 32768
    float*  refined5 = ws + 12333728;             // 737280
    float*  tpart    = ws + 13071008;             // 262144
    int*    amax     = (int*)(ws + 13333152);     // 18432
    int*    flag     = (int*)(ws + 13351584);     // 1
    int*    cand_cnt = (int*)(ws + 13351585);     // 1
    int*    cand_lst = (int*)(ws + 13351586);     // 18432
    float*  w1cT     = ws + 13370020;             // 294912
    float*  w2cT     = ws + 13664932;             // 36864
    float*  WcT      = ws + 13701796;             // 184320 -> ends 13886116

    // output offsets: ext | cls | ext2 | cls2
    float* out_ext  = out;
    float* out_cls  = out + 36864;
    float* out_ext2 = out + 2691072;
    float* out_cls2 = out + 2727936;

    dim3 blk(256);

    // weight prep (independent of x)
    wcomb_build<<<dim3(160, 4), blk, 0, stream>>>(
        ext_w1, ext_b1, ext_g, ext_bb, ext_m, ext_v, ext_w2, ext_b2,
        cls_w1, cls_b1, cls_g, cls_bb, cls_m, cls_v, cls_w2, cls_b2,
        Wc32, Wchi, Wclo, cconst);
    zero_counters<<<1, 1, 0, stream>>>(cand_cnt);
    transpose_w<<<dim3(36, 8), blk, 0, stream>>>(cls_w1, w1cT, 256, 1152);
    transpose_w<<<dim3(8, 5), blk, 0, stream>>>(cls_w2, w2cT, 144, 256);
    transpose_w<<<dim3(36, 5), blk, 0, stream>>>(Wc32, WcT, 160, 1152);

    // pass 1
    logits_gemm<<<dim3(144, NKS), blk, 0, stream>>>(x, Wchi, Wclo, logitsP);
    softmax_heads<0><<<4608, blk, 0, stream>>>(logitsP, cconst, out_cls, out_ext, amax, partials,
        cand_cnt, cand_lst, nullptr, nullptr, nullptr, nullptr);
    reduce_flag<<<1, blk, 0, stream>>>(partials, 4608, flag);
    fixup_list<<<256, blk, 0, stream>>>(cand_cnt, cand_lst, x,
        w1cT, cls_b1, cls_g, cls_bb, cls_m, cls_v, w2cT, cls_b2, amax);

    // refine chain (always computed; application predicated on flag)
    tok_partial<<<dim3(128, 8), blk, 0, stream>>>(x, amax, tok_w, tpart);
    attn_front<<<128, dim3(512), 0, stream>>>(tpart, tok_b, emb, ln1_g, ln1_b, qkv_w,
        out_w, out_b, ln2_g, ln2_b, z2_5, t5buf);
    ff1_gelu<<<dim3(128, 2), blk, 0, stream>>>(z2_5, ff_w1, ff_b1, f5buf);
    ff2_lnf<<<128, blk, 0, stream>>>(f5buf, ff_w2, ff_b2, t5buf, lnf_g, lnf_b, tfin);
    fin_gemm<<<dim3(23, 8), blk, 0, stream>>>(tfin, fin_w, fin_b, refined5);

    // pass 2 = pass 1 logits + rank-40 delta fused into softmax
    softmax_heads<1><<<4608, blk, 0, stream>>>(logitsP, cconst, out_cls2, out_ext2, amax, nullptr,
        nullptr, nullptr, x, WcT, refined5, flag);
}

// Round 12
// 307.821 us; speedup vs baseline: 1.6827x; 1.1186x over previous
//
#include <hip/hip_runtime.h>
#include <math.h>

#define EPSF 1e-5f
#define GAPTH 1e-3f
#define NKS 4           // K-split slices for logits GEMM (288 each)
#define KSL 288
#define RROWS 18432

// B=128, C=8, H=144, W=144, CW=1152, R=18432, TW=5, OG=2, NCLS=6, DT=256, ITC=5760
// Collapsed head: logits[row, j] = sum_k Wc[j,k] * x'[row,k] + cconst[j]
//   j 0..143 = cls, j 144..145 = ext, j 146..159 = zero pad. NP=160.
// Pass 2 = pass 1 + rank-40 per-row delta, fused into softmax (DELTA=1).

typedef __attribute__((ext_vector_type(8))) short short8v;
typedef __attribute__((ext_vector_type(4))) float f32x4;
typedef unsigned short ushort;
typedef unsigned int uint;

__device__ inline ushort f2bf(float f) {
    uint u = __float_as_uint(f);
    uint r = (u + 0x7FFFu + ((u >> 16) & 1u)) >> 16;
    return (ushort)r;
}
__device__ inline float bf2f(ushort h) { return __uint_as_float(((uint)h) << 16); }

// ---------------------------------------------------------------------------
// Build combined weights, K-split over blockIdx.y for occupancy.
// ---------------------------------------------------------------------------
__global__ __launch_bounds__(256) void wcomb_build(
    const float* __restrict__ w1e, const float* __restrict__ b1e, const float* __restrict__ ge,
    const float* __restrict__ bbe, const float* __restrict__ me, const float* __restrict__ ve,
    const float* __restrict__ w2e, const float* __restrict__ b2e,
    const float* __restrict__ w1c, const float* __restrict__ b1c, const float* __restrict__ gc,
    const float* __restrict__ bbc, const float* __restrict__ mc, const float* __restrict__ vc,
    const float* __restrict__ w2c, const float* __restrict__ b2c,
    float* __restrict__ Wc32, ushort* __restrict__ Wchi, ushort* __restrict__ Wclo,
    float* __restrict__ cconst)
{
    __shared__ float coef[256];
    __shared__ float csum[4];
    const int j = blockIdx.x, kq = blockIdx.y, tid = threadIdx.x;
    const int lane = tid & 63, wid = tid >> 6;

    const float *w1 = nullptr, *w2row = nullptr, *b1 = nullptr, *g = nullptr,
                *bb = nullptr, *m = nullptr, *v = nullptr;
    float b2v = 0.f;
    int valid = 0;
    if (j < 144) {
        valid = 1; w1 = w1c; w2row = w2c + (size_t)j * 256;
        b1 = b1c; g = gc; bb = bbc; m = mc; v = vc; b2v = b2c[j];
    } else if (j < 146) {
        valid = 1; w1 = w1e; w2row = w2e + (size_t)(j - 144) * 256;
        b1 = b1e; g = ge; bb = bbe; m = me; v = ve; b2v = b2e[j - 144];
    }

    float cf = 0.f, cc = 0.f;
    if (valid) {
        float s = g[tid] * rsqrtf(v[tid] + EPSF);
        float w2v = w2row[tid];
        cf = w2v * s;
        cc = w2v * ((b1[tid] - m[tid]) * s + bb[tid]);
    }
    coef[tid] = cf;
    if (kq == 0) {
        float t = cc;
#pragma unroll
        for (int off = 32; off; off >>= 1) t += __shfl_xor(t, off);
        if (lane == 0) csum[wid] = t;
    }
    __syncthreads();
    if (kq == 0 && tid == 0)
        cconst[j] = valid ? ((csum[0] + csum[1]) + (csum[2] + csum[3]) + b2v) : 0.f;

    for (int k = kq * KSL + tid; k < (kq + 1) * KSL; k += 256) {
        float acc = 0.f;
        if (valid) {
            for (int o = 0; o < 256; o++) acc += coef[o] * w1[(size_t)o * 1152 + k];
        }
        Wc32[(size_t)j * 1152 + k] = acc;
        ushort hi = f2bf(acc);
        Wchi[(size_t)j * 1152 + k] = hi;
        Wclo[(size_t)j * 1152 + k] = f2bf(acc - bf2f(hi));
    }
}

__global__ void zero_counters(int* __restrict__ cand_count)
{
    *cand_count = 0;
}

// ---------------------------------------------------------------------------
// tiled transpose: src[R][Cc] -> dst[Cc][R]
// ---------------------------------------------------------------------------
__global__ __launch_bounds__(256) void transpose_w(
    const float* __restrict__ src, float* __restrict__ dst, int R, int Cc)
{
    __shared__ float tile[32][33];
    const int rb = blockIdx.y * 32, cb = blockIdx.x * 32;
    const int tx = threadIdx.x & 31, ty = threadIdx.x >> 5;
#pragma unroll
    for (int i = ty; i < 32; i += 8) {
        int r = rb + i, c = cb + tx;
        tile[i][tx] = (r < R && c < Cc) ? src[(size_t)r * Cc + c] : 0.f;
    }
    __syncthreads();
#pragma unroll
    for (int i = ty; i < 32; i += 8) {
        int c = cb + i, r = rb + tx;
        if (c < Cc && r < R) dst[(size_t)c * R + r] = tile[tx][i];
    }
}

// ---------------------------------------------------------------------------
// logits GEMM: M=18432, N=160(146 used), K=1152 in NKS=4 slices of 288.
// BM=128, BN=160, BK=32; 4 waves as 2m x 2n; wave tile 64x80 (4x5 frags).
// ---------------------------------------------------------------------------
__global__ __launch_bounds__(256) void logits_gemm(
    const float* __restrict__ x, const ushort* __restrict__ Wchi, const ushort* __restrict__ Wclo,
    float* __restrict__ logits_part)
{
    __shared__ ushort Ahi[128][40], Alo[128][40], Bhi[160][40], Blo[160][40];
    const int tid = threadIdx.x;
    const int lane = tid & 63, wid = tid >> 6;
    const int wm = wid & 1, wn = wid >> 1;
    const int rb = blockIdx.x * 128;
    const int ks = blockIdx.y;
    const int kbase = ks * KSL;
    const int NIT = KSL / 32;                    // 9

    const int rl = tid >> 1, kq = (tid & 1) << 4;
    const int arow = rb + rl;
    const int ab = arow / 144, ahh = arow - ab * 144;
    const int br2 = 128 + (tid >> 1);

    float av[16];
    short8v vb0a, vb0b, vl0a, vl0b;
    short8v vb2a, vb2b, vl2a, vl2b;

    auto LOAD = [&](int kb) {
        const int k0 = kb + kq;
        const int c = k0 / 144, w = k0 - c * 144;
        const float* xp = x + (((size_t)(ab * 8 + c) * 144 + ahh) * 144 + w);
#pragma unroll
        for (int q = 0; q < 4; q++) {
            const float4 t4 = *reinterpret_cast<const float4*>(xp + q * 4);
            av[q * 4 + 0] = t4.x; av[q * 4 + 1] = t4.y;
            av[q * 4 + 2] = t4.z; av[q * 4 + 3] = t4.w;
        }
        const ushort* bh = Wchi + (size_t)rl * 1152 + k0;
        const ushort* bl = Wclo + (size_t)rl * 1152 + k0;
        vb0a = *reinterpret_cast<const short8v*>(bh);
        vb0b = *reinterpret_cast<const short8v*>(bh + 8);
        vl0a = *reinterpret_cast<const short8v*>(bl);
        vl0b = *reinterpret_cast<const short8v*>(bl + 8);
        if (tid < 64) {
            const ushort* bh2 = Wchi + (size_t)br2 * 1152 + k0;
            const ushort* bl2 = Wclo + (size_t)br2 * 1152 + k0;
            vb2a = *reinterpret_cast<const short8v*>(bh2);
            vb2b = *reinterpret_cast<const short8v*>(bh2 + 8);
            vl2a = *reinterpret_cast<const short8v*>(bl2);
            vl2b = *reinterpret_cast<const short8v*>(bl2 + 8);
        }
    };

    auto STORE = [&]() {
        short8v hv0, hv1, lv0, lv1;
#pragma unroll
        for (int q = 0; q < 8; q++) {
            ushort h = f2bf(av[q]);
            hv0[q] = (short)h; lv0[q] = (short)f2bf(av[q] - bf2f(h));
        }
#pragma unroll
        for (int q = 0; q < 8; q++) {
            ushort h = f2bf(av[8 + q]);
            hv1[q] = (short)h; lv1[q] = (short)f2bf(av[8 + q] - bf2f(h));
        }
        *reinterpret_cast<short8v*>(&Ahi[rl][kq]) = hv0;
        *reinterpret_cast<short8v*>(&Ahi[rl][kq + 8]) = hv1;
        *reinterpret_cast<short8v*>(&Alo[rl][kq]) = lv0;
        *reinterpret_cast<short8v*>(&Alo[rl][kq + 8]) = lv1;
        *reinterpret_cast<short8v*>(&Bhi[rl][kq]) = vb0a;
        *reinterpret_cast<short8v*>(&Bhi[rl][kq + 8]) = vb0b;
        *reinterpret_cast<short8v*>(&Blo[rl][kq]) = vl0a;
        *reinterpret_cast<short8v*>(&Blo[rl][kq + 8]) = vl0b;
        if (tid < 64) {
            *reinterpret_cast<short8v*>(&Bhi[br2][kq]) = vb2a;
            *reinterpret_cast<short8v*>(&Bhi[br2][kq + 8]) = vb2b;
            *reinterpret_cast<short8v*>(&Blo[br2][kq]) = vl2a;
            *reinterpret_cast<short8v*>(&Blo[br2][kq + 8]) = vl2b;
        }
    };

    f32x4 acc[4][5];
#pragma unroll
    for (int mt = 0; mt < 4; mt++)
#pragma unroll
        for (int nt = 0; nt < 5; nt++) acc[mt][nt] = (f32x4){0.f, 0.f, 0.f, 0.f};

    const int fr = lane & 15, fg = (lane >> 4) << 3;

    LOAD(kbase);
    for (int t = 0; t < NIT; t++) {
        STORE();
        if (t < NIT - 1) LOAD(kbase + (t + 1) * 32);
        __syncthreads();
        short8v ah[4], al[4];
#pragma unroll
        for (int mt = 0; mt < 4; mt++) {
            ah[mt] = *reinterpret_cast<const short8v*>(&Ahi[wm * 64 + mt * 16 + fr][fg]);
            al[mt] = *reinterpret_cast<const short8v*>(&Alo[wm * 64 + mt * 16 + fr][fg]);
        }
#pragma unroll
        for (int nt = 0; nt < 5; nt++) {
            short8v bh = *reinterpret_cast<const short8v*>(&Bhi[wn * 80 + nt * 16 + fr][fg]);
            short8v bl = *reinterpret_cast<const short8v*>(&Blo[wn * 80 + nt * 16 + fr][fg]);
#pragma unroll
            for (int mt = 0; mt < 4; mt++) {
                acc[mt][nt] = __builtin_amdgcn_mfma_f32_16x16x32_bf16(ah[mt], bh, acc[mt][nt], 0, 0, 0);
                acc[mt][nt] = __builtin_amdgcn_mfma_f32_16x16x32_bf16(ah[mt], bl, acc[mt][nt], 0, 0, 0);
                acc[mt][nt] = __builtin_amdgcn_mfma_f32_16x16x32_bf16(al[mt], bh, acc[mt][nt], 0, 0, 0);
            }
        }
        __syncthreads();
    }

    float* base = logits_part + (size_t)ks * RROWS * 160;
#pragma unroll
    for (int mt = 0; mt < 4; mt++) {
#pragma unroll
        for (int nt = 0; nt < 5; nt++) {
            int gcol = wn * 80 + nt * 16 + fr;
            if (gcol < 146) {
                float* dst = base + (size_t)(rb + wm * 64 + mt * 16 + ((lane >> 4) << 2)) * 160 + gcol;
#pragma unroll
                for (int i = 0; i < 4; i++)
                    dst[(size_t)i * 160] = acc[mt][nt][i];
            }
        }
    }
}

// ---------------------------------------------------------------------------
// merged softmax over summed K-slices; DELTA=1 adds rank-40 per-row patch delta.
// ---------------------------------------------------------------------------
template<int DELTA>
__global__ __launch_bounds__(256) void softmax_heads(
    const float* __restrict__ logits_part, const float* __restrict__ cconst,
    float* __restrict__ out_cls, float* __restrict__ out_ext,
    int* __restrict__ amax, float* __restrict__ partials,
    int* __restrict__ cand_count, int* __restrict__ cand_list,
    const float* __restrict__ x, const float* __restrict__ WcT,
    const float* __restrict__ refined5, const int* __restrict__ flag)
{
    __shared__ float ps[4];
    __shared__ float dL[4][148];
    __shared__ float dsh[4][40];
    __shared__ int   ksh[4][40];
    const int r4 = threadIdx.x >> 6, lane = threadIdx.x & 63;
    const int row = blockIdx.x * 4 + r4;

    if (DELTA) {
        const int fl = *flag;
        if (fl) {
            const int b = row / 144, hh = row - b * 144;
            const int a = amax[row];
            if (lane < 40) {
                int c = lane / 5, tw = lane - c * 5;
                int w = a - 2 + tw;
                float d = 0.f; int k = 0;
                if (w >= 0 && w < 144) {
                    k = c * 144 + w;
                    d = refined5[(size_t)b * 5760 + (c * 144 + hh) * 5 + tw]
                      - x[((size_t)(b * 8 + c) * 144 + hh) * 144 + w];
                }
                dsh[r4][lane] = d; ksh[r4][lane] = k;
            }
            __syncthreads();
#pragma unroll
            for (int rj = 0; rj < 3; rj++) {
                int j = lane + rj * 64;
                if (j < 146) {
                    float acc = 0.f;
#pragma unroll 8
                    for (int i = 0; i < 40; i++)
                        acc += WcT[(size_t)ksh[r4][i] * 160 + j] * dsh[r4][i];
                    dL[r4][j] = acc;
                }
            }
        } else {
#pragma unroll
            for (int rj = 0; rj < 3; rj++) {
                int j = lane + rj * 64;
                if (j < 146) dL[r4][j] = 0.f;
            }
        }
        __syncthreads();
    }

    const float* L0 = logits_part + (size_t)row * 160;
    const float* L1 = L0 + (size_t)RROWS * 160;
    const float* L2 = L1 + (size_t)RROWS * 160;
    const float* L3 = L2 + (size_t)RROWS * 160;
    float v0 = L0[lane] + L1[lane] + L2[lane] + L3[lane] + cconst[lane];
    float v1 = L0[lane + 64] + L1[lane + 64] + L2[lane + 64] + L3[lane + 64] + cconst[lane + 64];
    float v2 = (lane < 16) ? (L0[lane + 128] + L1[lane + 128] + L2[lane + 128] + L3[lane + 128]
                              + cconst[lane + 128])
                           : -3.0e38f;
    if (DELTA) {
        v0 += dL[r4][lane];
        v1 += dL[r4][lane + 64];
        if (lane < 16) v2 += dL[r4][lane + 128];
    }
    float m = v0; int mi = lane;
    if (v1 > m) { m = v1; mi = lane + 64; }
    if (v2 > m) { m = v2; mi = lane + 128; }
    float m1 = v0, m2 = -3.0e38f;
    if (v1 > m1) { m2 = m1; m1 = v1; } else m2 = v1;
    if (v2 > m1) { m2 = m1; m1 = v2; } else m2 = fmaxf(m2, v2);
#pragma unroll
    for (int off = 32; off; off >>= 1) {
        float om = __shfl_xor(m, off);
        int   oi = __shfl_xor(mi, off);
        if (om > m || (om == m && oi < mi)) { m = om; mi = oi; }
        float om1 = __shfl_xor(m1, off);
        float om2 = __shfl_xor(m2, off);
        float nm1 = fmaxf(m1, om1);
        m2 = fmaxf(fminf(m1, om1), fmaxf(m2, om2));
        m1 = nm1;
    }
    float e0 = expf(v0 - m), e1 = expf(v1 - m);
    float e2 = (lane < 16) ? expf(v2 - m) : 0.f;
    float s = e0 + e1 + e2;
#pragma unroll
    for (int off = 32; off; off >>= 1) s += __shfl_xor(s, off);
    float inv = 1.f / s;
    float* O = out_cls + (size_t)row * 144;
    O[lane] = e0 * inv;
    O[lane + 64] = e1 * inv;
    if (lane < 16) O[lane + 128] = e2 * inv;

    float l0 = L0[144] + L1[144] + L2[144] + L3[144] + cconst[144];
    float l1 = L0[145] + L1[145] + L2[145] + L3[145] + cconst[145];
    if (DELTA) { l0 += dL[r4][144]; l1 += dL[r4][145]; }
    float mx = fmaxf(l0, l1);
    float ee0 = expf(l0 - mx), ee1 = expf(l1 - mx);
    float einv = 1.f / (ee0 + ee1);
    float p0 = ee0 * einv;
    if (lane == 0) {
        out_ext[(size_t)row * 2] = p0;
        out_ext[(size_t)row * 2 + 1] = ee1 * einv;
        if (amax != nullptr && !DELTA) {
            amax[row] = mi;
            if (m1 - m2 < GAPTH) {
                int slot = atomicAdd(cand_count, 1);
                cand_list[slot] = row;
            }
        }
    }
    if (partials != nullptr) {
        if (lane == 0) ps[r4] = p0;
        __syncthreads();
        if (threadIdx.x == 0) partials[blockIdx.x] = (ps[0] + ps[1]) + (ps[2] + ps[3]);
    }
}

__global__ __launch_bounds__(256) void reduce_flag(const float* __restrict__ partials, int n,
                                                   int* __restrict__ flag)
{
    __shared__ float sm[256];
    int tid = threadIdx.x;
    float s = 0.f;
    for (int i = tid; i < n; i += 256) s += partials[i];
    sm[tid] = s; __syncthreads();
    for (int off = 128; off; off >>= 1) {
        if (tid < off) sm[tid] += sm[tid + off];
        __syncthreads();
    }
    if (tid == 0) *flag = (sm[0] * (1.f / 18432.f) > 0.3f) ? 1 : 0;
}

// ---------------------------------------------------------------------------
// fixup over compacted candidate list: exact f32 two-stage recompute of argmax.
// ---------------------------------------------------------------------------
__global__ __launch_bounds__(256) void fixup_list(
    const int* __restrict__ cand_count, const int* __restrict__ cand_list,
    const float* __restrict__ x,
    const float* __restrict__ w1cT, const float* __restrict__ b1c,
    const float* __restrict__ gc, const float* __restrict__ bbc,
    const float* __restrict__ mc, const float* __restrict__ vc,
    const float* __restrict__ w2cT, const float* __restrict__ b2c,
    int* __restrict__ amax)
{
    __shared__ float xrow[1152];
    __shared__ float hsh[256];
    __shared__ float Lsh[144];
    const int tid = threadIdx.x;
    const int n = *cand_count;

    for (int ci = blockIdx.x; ci < n; ci += gridDim.x) {
        const int row = cand_list[ci];
        const int b = row / 144, hh = row - b * 144;
        for (int e = tid; e < 1152; e += 256) {
            int c = e / 144, w = e - c * 144;
            xrow[e] = x[(((size_t)(b * 8 + c) * 144 + hh) * 144) + w];
        }
        __syncthreads();
        {
            float a = 0.f;
#pragma unroll 8
            for (int k = 0; k < 1152; k++) a += w1cT[(size_t)k * 256 + tid] * xrow[k];
            float sc = gc[tid] * rsqrtf(vc[tid] + EPSF);
            hsh[tid] = (a + b1c[tid] - mc[tid]) * sc + bbc[tid];
        }
        __syncthreads();
        if (tid < 144) {
            float a = 0.f;
#pragma unroll 8
            for (int k = 0; k < 256; k++) a += w2cT[(size_t)k * 144 + tid] * hsh[k];
            Lsh[tid] = a + b2c[tid];
        }
        __syncthreads();
        if (tid == 0) {
            int bi = 0; float bv = Lsh[0];
            for (int j = 1; j < 144; j++) if (Lsh[j] > bv) { bv = Lsh[j]; bi = j; }
            amax[row] = bi;
        }
        __syncthreads();
    }
}

// ---------------------------------------------------------------------------
// tok GEMM with fused patch gather; 4 accumulators for ILP.
// ---------------------------------------------------------------------------
__global__ __launch_bounds__(256) void tok_partial(const float* __restrict__ x,
    const int* __restrict__ amax, const float* __restrict__ tok_w, float* __restrict__ tpart)
{
    __shared__ float P[720];
    __shared__ int ash[144];
    int b = blockIdx.x, c = blockIdx.y, tid = threadIdx.x;
    if (tid < 144) ash[tid] = amax[b * 144 + tid];
    __syncthreads();
    for (int e = tid; e < 720; e += 256) {
        int hh = e / 5, tw = e - hh * 5;
        int w = ash[hh] + tw - 2;
        P[e] = (w >= 0 && w < 144) ? x[(((size_t)(b * 8 + c) * 144 + hh) * 144) + w] : 0.f;
    }
    __syncthreads();
    const float* wbase = tok_w + (size_t)c * 720 * 256;
    float a0 = 0.f, a1 = 0.f, a2 = 0.f, a3 = 0.f;
    for (int k = 0; k < 720; k += 4) {
        a0 += P[k]     * wbase[(size_t)k * 256 + tid];
        a1 += P[k + 1] * wbase[(size_t)(k + 1) * 256 + tid];
        a2 += P[k + 2] * wbase[(size_t)(k + 2) * 256 + tid];
        a3 += P[k + 3] * wbase[(size_t)(k + 3) * 256 + tid];
    }
    tpart[((size_t)b * 8 + c) * 256 + tid] = (a0 + a1) + (a2 + a3);
}

// ---------------------------------------------------------------------------
// attn_front: tok_finish + LN1(x6) + qkv (q only token 5) + attention row 5
// + out-proj token 5 + residual + LN2.  512 threads; serial dots broken into
// 4-lane k-split groups with shfl reduce (latency fix).
// ---------------------------------------------------------------------------
__global__ __launch_bounds__(512) void attn_front(
    const float* __restrict__ tpart, const float* __restrict__ tok_b,
    const float* __restrict__ emb,
    const float* __restrict__ ln1_g, const float* __restrict__ ln1_b,
    const float* __restrict__ qkv_w,
    const float* __restrict__ out_w, const float* __restrict__ out_b,
    const float* __restrict__ ln2_g, const float* __restrict__ ln2_b,
    float* __restrict__ z2_5, float* __restrict__ t5out)
{
    __shared__ float s[256];
    __shared__ float z[6][256];
    __shared__ float qk[6][192];
    __shared__ float att[2][6];
    __shared__ float o5[64];
    __shared__ float t5[256];
    __shared__ float stat[2];
    const int b = blockIdx.x, tid = threadIdx.x;
    const int lane = tid & 63, wv = tid >> 6;
    const int g4 = tid >> 2, l4 = tid & 3;

    if (tid < 256) {
        float a = tok_b[tid];
#pragma unroll
        for (int ks = 0; ks < 8; ks++) a += tpart[((size_t)b * 8 + ks) * 256 + tid];
        s[tid] = a;
    }
    __syncthreads();

    // LN1: wave wv handles token wv (wv<6)
    if (wv < 6) {
        float y[4], s1 = 0.f, s2 = 0.f;
#pragma unroll
        for (int q = 0; q < 4; q++) {
            int k = lane + 64 * q;
            y[q] = s[k] + emb[wv * 256 + k];
            s1 += y[q]; s2 += y[q] * y[q];
        }
#pragma unroll
        for (int off = 32; off; off >>= 1) { s1 += __shfl_xor(s1, off); s2 += __shfl_xor(s2, off); }
        float mu = s1 * (1.f / 256.f);
        float var = s2 * (1.f / 256.f) - mu * mu;
        float rs = rsqrtf(var + EPSF);
#pragma unroll
        for (int q = 0; q < 4; q++) {
            int k = lane + 64 * q;
            z[wv][k] = (y[q] - mu) * rs * ln1_g[k] + ln1_b[k];
        }
    }
    __syncthreads();

    // qkv dots, 4-lane k-split (interleaved k -> conflict-free LDS):
    // tt<768 -> k/v token i=tt>>7, col c=64+(tt&127); tt>=768 -> q5, c=tt-768
    for (int tt = g4; tt < 832; tt += 128) {
        int i, c;
        if (tt < 768) { i = tt >> 7; c = 64 + (tt & 127); }
        else          { i = 5;       c = tt - 768; }
        float a = 0.f;
#pragma unroll 8
        for (int j = 0; j < 64; j++) {
            int k = l4 + 4 * j;
            a += z[i][k] * qkv_w[(size_t)k * 192 + c];
        }
        a += __shfl_xor(a, 1);
        a += __shfl_xor(a, 2);
        if (l4 == 0) qk[i][c] = a;
    }
    __syncthreads();

    // attention row 5 only
    if (tid < 12) {
        int h = tid / 6, j = tid - h * 6;
        float a = 0.f;
#pragma unroll
        for (int d = 0; d < 32; d++) a += qk[5][h * 32 + d] * qk[j][64 + h * 32 + d];
        att[h][j] = a * 0.17677669529663687f;
    }
    __syncthreads();
    if (tid < 2) {
        float m = -3.0e38f;
        for (int j = 0; j < 6; j++) m = fmaxf(m, att[tid][j]);
        float ssum = 0.f;
        for (int j = 0; j < 6; j++) { float e = expf(att[tid][j] - m); att[tid][j] = e; ssum += e; }
        float inv = 1.f / ssum;
        for (int j = 0; j < 6; j++) att[tid][j] *= inv;
    }
    __syncthreads();
    if (tid < 64) {
        int h = tid >> 5;
        float a = 0.f;
#pragma unroll
        for (int j = 0; j < 6; j++) a += att[h][j] * qk[j][128 + tid];
        o5[tid] = a;
    }
    __syncthreads();

    // out-proj token 5 + residual, 4-lane d-split
    for (int tt = g4; tt < 256; tt += 128) {
        float a = 0.f;
#pragma unroll
        for (int j = 0; j < 16; j++) {
            int d = l4 + 4 * j;
            a += o5[d] * out_w[(size_t)d * 256 + tt];
        }
        a += __shfl_xor(a, 1);
        a += __shfl_xor(a, 2);
        if (l4 == 0) t5[tt] = a + out_b[tt] + s[tt] + emb[5 * 256 + tt];
    }
    __syncthreads();

    // LN2 stats (wave 0)
    if (wv == 0) {
        float s1 = 0.f, s2 = 0.f;
#pragma unroll
        for (int q = 0; q < 4; q++) { float vv = t5[lane + 64 * q]; s1 += vv; s2 += vv * vv; }
#pragma unroll
        for (int off = 32; off; off >>= 1) { s1 += __shfl_xor(s1, off); s2 += __shfl_xor(s2, off); }
        if (lane == 0) {
            float mu = s1 * (1.f / 256.f);
            float var = s2 * (1.f / 256.f) - mu * mu;
            stat[0] = mu; stat[1] = rsqrtf(var + EPSF);
        }
    }
    __syncthreads();
    if (tid < 256) {
        t5out[(size_t)b * 256 + tid] = t5[tid];
        z2_5[(size_t)b * 256 + tid] = (t5[tid] - stat[0]) * stat[1] * ln2_g[tid] + ln2_b[tid];
    }
}

// ---------------------------------------------------------------------------
// ff1 + exact gelu for token 5: 4-lane k-split, 512 threads
// ---------------------------------------------------------------------------
__global__ __launch_bounds__(512) void ff1_gelu(
    const float* __restrict__ z2_5, const float* __restrict__ ff_w1,
    const float* __restrict__ ff_b1, float* __restrict__ f5)
{
    __shared__ float zsh[256];
    const int b = blockIdx.x, half = blockIdx.y, tid = threadIdx.x;
    const int g4 = tid >> 2, l4 = tid & 3;
    if (tid < 256) zsh[tid] = z2_5[(size_t)b * 256 + tid];
    __syncthreads();
    for (int tt = g4; tt < 256; tt += 128) {
        const int jj = half * 256 + tt;
        float a = 0.f;
#pragma unroll 8
        for (int j = 0; j < 64; j++) {
            int k = l4 + 4 * j;
            a += zsh[k] * ff_w1[(size_t)k * 512 + jj];
        }
        a += __shfl_xor(a, 1);
        a += __shfl_xor(a, 2);
        if (l4 == 0) {
            a += ff_b1[jj];
            f5[(size_t)b * 512 + jj] = 0.5f * a * (1.f + erff(a * 0.70710678118654752f));
        }
    }
}

// ---------------------------------------------------------------------------
// ff2 + residual + LNF for token 5 -> tfin: 4-lane k-split, 512 threads
// ---------------------------------------------------------------------------
__global__ __launch_bounds__(512) void ff2_lnf(
    const float* __restrict__ f5, const float* __restrict__ ff_w2,
    const float* __restrict__ ff_b2, const float* __restrict__ t5in,
    const float* __restrict__ lnf_g, const float* __restrict__ lnf_b,
    float* __restrict__ tfin)
{
    __shared__ float fsh[512];
    __shared__ float tsh[256];
    __shared__ float stat[2];
    const int b = blockIdx.x, tid = threadIdx.x;
    const int lane = tid & 63, wv = tid >> 6;
    const int g4 = tid >> 2, l4 = tid & 3;
    fsh[tid] = f5[(size_t)b * 512 + tid];
    __syncthreads();
    for (int tt = g4; tt < 256; tt += 128) {
        float a = 0.f;
#pragma unroll 8
        for (int j = 0; j < 128; j++) {
            int k = l4 + 4 * j;
            a += fsh[k] * ff_w2[(size_t)k * 256 + tt];
        }
        a += __shfl_xor(a, 1);
        a += __shfl_xor(a, 2);
        if (l4 == 0) tsh[tt] = a + ff_b2[tt] + t5in[(size_t)b * 256 + tt];
    }
    __syncthreads();
    if (wv == 0) {
        float s1 = 0.f, s2 = 0.f;
#pragma unroll
        for (int q = 0; q < 4; q++) { float vv = tsh[lane + 64 * q]; s1 += vv; s2 += vv * vv; }
#pragma unroll
        for (int off = 32; off; off >>= 1) { s1 += __shfl_xor(s1, off); s2 += __shfl_xor(s2, off); }
        if (lane == 0) {
            float mu = s1 * (1.f / 256.f);
            float var = s2 * (1.f / 256.f) - mu * mu;
            stat[0] = mu; stat[1] = rsqrtf(var + EPSF);
        }
    }
    __syncthreads();
    if (tid < 256)
        tfin[(size_t)b * 256 + tid] = (tsh[tid] - stat[0]) * stat[1] * lnf_g[tid] + lnf_b[tid];
}

// ---------------------------------------------------------------------------
// fin GEMM for token 5: refined5[b,n] = tfin[b,:] @ fin_w[:,n] + fin_b[n]
// ---------------------------------------------------------------------------
__global__ __launch_bounds__(256) void fin_gemm(const float* __restrict__ tfin,
    const float* __restrict__ fin_w, const float* __restrict__ fin_b, float* __restrict__ refined5)
{
    __shared__ float tf[16][256];
    int tid = threadIdx.x;
    int nb = blockIdx.x * 256 + tid;
    int bg = blockIdx.y * 16;
    for (int e = tid; e < 4096; e += 256) tf[e >> 8][e & 255] = tfin[(size_t)(bg + (e >> 8)) * 256 + (e & 255)];
    __syncthreads();
    if (nb < 5760) {
        float acc[16];
#pragma unroll
        for (int bb = 0; bb < 16; bb++) acc[bb] = 0.f;
        for (int k = 0; k < 256; k++) {
            float wv = fin_w[(size_t)k * 5760 + nb];
#pragma unroll
            for (int bb = 0; bb < 16; bb++) acc[bb] += tf[bb][k] * wv;
        }
        float fb = fin_b[nb];
#pragma unroll
        for (int bb = 0; bb < 16; bb++)
            refined5[(size_t)(bg + bb) * 5760 + nb] = acc[bb] + fb;
    }
}

// ---------------------------------------------------------------------------
extern "C" void kernel_launch(void* const* d_in, const int* in_sizes, int n_in,
                              void* d_out, int out_size, void* d_ws, size_t ws_size,
                              hipStream_t stream)
{
    const float* x      = (const float*)d_in[0];
    const float* ext_w1 = (const float*)d_in[1];
    const float* ext_b1 = (const float*)d_in[2];
    const float* ext_g  = (const float*)d_in[3];
    const float* ext_bb = (const float*)d_in[4];
    const float* ext_m  = (const float*)d_in[5];
    const float* ext_v  = (const float*)d_in[6];
    const float* ext_w2 = (const float*)d_in[7];
    const float* ext_b2 = (const float*)d_in[8];
    const float* cls_w1 = (const float*)d_in[9];
    const float* cls_b1 = (const float*)d_in[10];
    const float* cls_g  = (const float*)d_in[11];
    const float* cls_bb = (const float*)d_in[12];
    const float* cls_m  = (const float*)d_in[13];
    const float* cls_v  = (const float*)d_in[14];
    const float* cls_w2 = (const float*)d_in[15];
    const float* cls_b2 = (const float*)d_in[16];
    const float* tok_w  = (const float*)d_in[17];
    const float* tok_b  = (const float*)d_in[18];
    const float* emb    = (const float*)d_in[19];
    const float* ln1_g  = (const float*)d_in[20];
    const float* ln1_b  = (const float*)d_in[21];
    const float* qkv_w  = (const float*)d_in[22];
    const float* out_w  = (const float*)d_in[23];
    const float* out_b  = (const float*)d_in[24];
    const float* ln2_g  = (const float*)d_in[25];
    const float* ln2_b  = (const float*)d_in[26];
    const float* ff_w1  = (const float*)d_in[27];
    const float* ff_b1  = (const float*)d_in[28];
    const float* ff_w2  = (const float*)d_in[29];
    const float* ff_b2  = (const float*)d_in[30];
    const float* lnf_g  = (const float*)d_in[31];
    const float* lnf_b  = (const float*)d_in[32];
    const float* fin_w  = (const float*)d_in[33];
    const float* fin_b  = (const float*)d_in[34];

    float* out = (float*)d_out;
    float* ws  = (float*)d_ws;

    // workspace layout (float offsets)
    float*  Wc32     = ws;                        // 184320
    float*  cconst   = ws + 184320;               // 160
    ushort* Wchi     = (ushort*)(ws + 184480);    // 92160 floats
    ushort* Wclo     = (ushort*)(ws + 276640);    // 92160 floats
    float*  logitsP  = ws + 368800;               // 4*18432*160 = 11796480
    float*  partials = ws + 12165280;             // 4608
    float*  z2_5     = ws + 12169888;             // 32768
    float*  t5buf    = ws + 12202656;             // 32768
    float*  f5buf    = ws + 12235424;             // 65536
    float*  tfin     = ws + 12300960;             // 32768
    float*  refined5 = ws + 12333728;             // 737280
    float*  tpart    = ws + 13071008;             // 262144
    int*    amax     = (int*)(ws + 13333152);     // 18432
    int*    flag     = (int*)(ws + 13351584);     // 1
    int*    cand_cnt = (int*)(ws + 13351585);     // 1
    int*    cand_lst = (int*)(ws + 13351586);     // 18432
    float*  w1cT     = ws + 13370020;             // 294912
    float*  w2cT     = ws + 13664932;             // 36864
    float*  WcT      = ws + 13701796;             // 184320 -> ends 13886116

    // output offsets: ext | cls | ext2 | cls2
    float* out_ext  = out;
    float* out_cls  = out + 36864;
    float* out_ext2 = out + 2691072;
    float* out_cls2 = out + 2727936;

    dim3 blk(256);

    // weight prep (independent of x)
    wcomb_build<<<dim3(160, 4), blk, 0, stream>>>(
        ext_w1, ext_b1, ext_g, ext_bb, ext_m, ext_v, ext_w2, ext_b2,
        cls_w1, cls_b1, cls_g, cls_bb, cls_m, cls_v, cls_w2, cls_b2,
        Wc32, Wchi, Wclo, cconst);
    zero_counters<<<1, 1, 0, stream>>>(cand_cnt);
    transpose_w<<<dim3(36, 8), blk, 0, stream>>>(cls_w1, w1cT, 256, 1152);
    transpose_w<<<dim3(8, 5), blk, 0, stream>>>(cls_w2, w2cT, 144, 256);
    transpose_w<<<dim3(36, 5), blk, 0, stream>>>(Wc32, WcT, 160, 1152);

    // pass 1
    logits_gemm<<<dim3(144, NKS), blk, 0, stream>>>(x, Wchi, Wclo, logitsP);
    softmax_heads<0><<<4608, blk, 0, stream>>>(logitsP, cconst, out_cls, out_ext, amax, partials,
        cand_cnt, cand_lst, nullptr, nullptr, nullptr, nullptr);
    reduce_flag<<<1, blk, 0, stream>>>(partials, 4608, flag);
    fixup_list<<<256, blk, 0, stream>>>(cand_cnt, cand_lst, x,
        w1cT, cls_b1, cls_g, cls_bb, cls_m, cls_v, w2cT, cls_b2, amax);

    // refine chain (always computed; application predicated on flag)
    tok_partial<<<dim3(128, 8), blk, 0, stream>>>(x, amax, tok_w, tpart);
    attn_front<<<128, dim3(512), 0, stream>>>(tpart, tok_b, emb, ln1_g, ln1_b, qkv_w,
        out_w, out_b, ln2_g, ln2_b, z2_5, t5buf);
    ff1_gelu<<<dim3(128, 2), dim3(512), 0, stream>>>(z2_5, ff_w1, ff_b1, f5buf);
    ff2_lnf<<<128, dim3(512), 0, stream>>>(f5buf, ff_w2, ff_b2, t5buf, lnf_g, lnf_b, tfin);
    fin_gemm<<<dim3(23, 8), blk, 0, stream>>>(tfin, fin_w, fin_b, refined5);

    // pass 2 = pass 1 logits + rank-40 delta fused into softmax
    softmax_heads<1><<<4608, blk, 0, stream>>>(logitsP, cconst, out_cls2, out_ext2, amax, nullptr,
        nullptr, nullptr, x, WcT, refined5, flag);
}

// Round 13
// 278.326 us; speedup vs baseline: 1.8610x; 1.1060x over previous
//
#include <hip/hip_runtime.h>
#include <math.h>

#define EPSF 1e-5f
#define GAPTH 2e-4f     // MFMA logit err ~3e-6; 30-70x margin (9 rounds, 0 flips at 1e-3)
#define NKS 2           // K-split slices for logits GEMM (576 each)
#define KSL 576
#define RROWS 18432

// B=128, C=8, H=144, W=144, CW=1152, R=18432, TW=5, OG=2, NCLS=6, DT=256, ITC=5760
// Collapsed head: logits[row, j] = sum_k Wc[j,k] * x'[row,k] + cconst[j]
//   j 0..143 = cls, j 144..145 = ext, j 146..159 = zero pad. NP=160.
// Pass 2 = pass 1 + rank-40 per-row delta, fused into softmax (DELTA=1).

typedef __attribute__((ext_vector_type(8))) short short8v;
typedef __attribute__((ext_vector_type(4))) float f32x4;
typedef unsigned short ushort;
typedef unsigned int uint;

__device__ inline ushort f2bf(float f) {
    uint u = __float_as_uint(f);
    uint r = (u + 0x7FFFu + ((u >> 16) & 1u)) >> 16;
    return (ushort)r;
}
__device__ inline float bf2f(ushort h) { return __uint_as_float(((uint)h) << 16); }

// ---------------------------------------------------------------------------
// Build combined weights, K-split over blockIdx.y for occupancy.
// ---------------------------------------------------------------------------
__global__ __launch_bounds__(256) void wcomb_build(
    const float* __restrict__ w1e, const float* __restrict__ b1e, const float* __restrict__ ge,
    const float* __restrict__ bbe, const float* __restrict__ me, const float* __restrict__ ve,
    const float* __restrict__ w2e, const float* __restrict__ b2e,
    const float* __restrict__ w1c, const float* __restrict__ b1c, const float* __restrict__ gc,
    const float* __restrict__ bbc, const float* __restrict__ mc, const float* __restrict__ vc,
    const float* __restrict__ w2c, const float* __restrict__ b2c,
    float* __restrict__ Wc32, ushort* __restrict__ Wchi, ushort* __restrict__ Wclo,
    float* __restrict__ cconst)
{
    __shared__ float coef[256];
    __shared__ float csum[4];
    const int j = blockIdx.x, kq = blockIdx.y, tid = threadIdx.x;
    const int lane = tid & 63, wid = tid >> 6;

    const float *w1 = nullptr, *w2row = nullptr, *b1 = nullptr, *g = nullptr,
                *bb = nullptr, *m = nullptr, *v = nullptr;
    float b2v = 0.f;
    int valid = 0;
    if (j < 144) {
        valid = 1; w1 = w1c; w2row = w2c + (size_t)j * 256;
        b1 = b1c; g = gc; bb = bbc; m = mc; v = vc; b2v = b2c[j];
    } else if (j < 146) {
        valid = 1; w1 = w1e; w2row = w2e + (size_t)(j - 144) * 256;
        b1 = b1e; g = ge; bb = bbe; m = me; v = ve; b2v = b2e[j - 144];
    }

    float cf = 0.f, cc = 0.f;
    if (valid) {
        float s = g[tid] * rsqrtf(v[tid] + EPSF);
        float w2v = w2row[tid];
        cf = w2v * s;
        cc = w2v * ((b1[tid] - m[tid]) * s + bb[tid]);
    }
    coef[tid] = cf;
    if (kq == 0) {
        float t = cc;
#pragma unroll
        for (int off = 32; off; off >>= 1) t += __shfl_xor(t, off);
        if (lane == 0) csum[wid] = t;
    }
    __syncthreads();
    if (kq == 0 && tid == 0)
        cconst[j] = valid ? ((csum[0] + csum[1]) + (csum[2] + csum[3]) + b2v) : 0.f;

    for (int k = kq * 288 + tid; k < (kq + 1) * 288; k += 256) {
        float acc = 0.f;
        if (valid) {
            for (int o = 0; o < 256; o++) acc += coef[o] * w1[(size_t)o * 1152 + k];
        }
        Wc32[(size_t)j * 1152 + k] = acc;
        ushort hi = f2bf(acc);
        Wchi[(size_t)j * 1152 + k] = hi;
        Wclo[(size_t)j * 1152 + k] = f2bf(acc - bf2f(hi));
    }
}

__global__ void zero_counters(int* __restrict__ cand_count)
{
    *cand_count = 0;
}

// ---------------------------------------------------------------------------
// tiled transpose: src[R][Cc] -> dst[Cc][R]
// ---------------------------------------------------------------------------
__global__ __launch_bounds__(256) void transpose_w(
    const float* __restrict__ src, float* __restrict__ dst, int R, int Cc)
{
    __shared__ float tile[32][33];
    const int rb = blockIdx.y * 32, cb = blockIdx.x * 32;
    const int tx = threadIdx.x & 31, ty = threadIdx.x >> 5;
#pragma unroll
    for (int i = ty; i < 32; i += 8) {
        int r = rb + i, c = cb + tx;
        tile[i][tx] = (r < R && c < Cc) ? src[(size_t)r * Cc + c] : 0.f;
    }
    __syncthreads();
#pragma unroll
    for (int i = ty; i < 32; i += 8) {
        int c = cb + i, r = rb + tx;
        if (c < Cc && r < R) dst[(size_t)c * R + r] = tile[tx][i];
    }
}

// ---------------------------------------------------------------------------
// logits GEMM: M=18432, N=160(146 used), K=1152 in NKS=2 slices of 576.
// BM=64, BN=160, BK=32; 4 waves as 2m x 2n; wave tile 32x80 (2x5 frags).
// Split-bf16 MFMA (hi/lo, 3 products). Writes per-slice partials.
// ---------------------------------------------------------------------------
__global__ __launch_bounds__(256) void logits_gemm(
    const float* __restrict__ x, const ushort* __restrict__ Wchi, const ushort* __restrict__ Wclo,
    float* __restrict__ logits_part)
{
    __shared__ ushort Ahi[64][40], Alo[64][40], Bhi[160][40], Blo[160][40];
    const int tid = threadIdx.x;
    const int lane = tid & 63, wid = tid >> 6;
    const int wm = wid & 1, wn = wid >> 1;
    const int rb = blockIdx.x * 64;
    const int ks = blockIdx.y;
    const int kbase = ks * KSL;
    const int NIT = KSL / 32;                    // 18

    // A staging: thread t loads row t>>2, 8 contiguous k at (t&3)*8
    const int rl = tid >> 2, kk = (tid & 3) << 3;
    const int arow = rb + rl;
    const int ab = arow / 144, ahh = arow - ab * 144;

    // B staging: rows 0..63 (+64..127) same mapping; rows 128..159 by tid<128
    const int br0 = tid >> 2, bk0 = (tid & 3) << 3;
    const int br2 = 128 + (tid >> 2), bk2 = (tid & 3) << 3;

    float av[8];
    short8v vbh0, vbl0, vbh1, vbl1, vbh2, vbl2;

    auto LOAD = [&](int kb) {
        int k1 = kb + kk, c1 = k1 / 144, w1 = k1 - c1 * 144;   // 8-chunk stays in one c
        const float4 t0 = *reinterpret_cast<const float4*>(
            x + (((size_t)(ab * 8 + c1) * 144 + ahh) * 144 + w1));
        const float4 t1 = *reinterpret_cast<const float4*>(
            x + (((size_t)(ab * 8 + c1) * 144 + ahh) * 144 + w1 + 4));
        av[0] = t0.x; av[1] = t0.y; av[2] = t0.z; av[3] = t0.w;
        av[4] = t1.x; av[5] = t1.y; av[6] = t1.z; av[7] = t1.w;
        size_t o0 = (size_t)br0 * 1152 + kb + bk0;
        vbh0 = *reinterpret_cast<const short8v*>(Wchi + o0);
        vbl0 = *reinterpret_cast<const short8v*>(Wclo + o0);
        size_t o1 = (size_t)(br0 + 64) * 1152 + kb + bk0;
        vbh1 = *reinterpret_cast<const short8v*>(Wchi + o1);
        vbl1 = *reinterpret_cast<const short8v*>(Wclo + o1);
        if (tid < 128) {
            size_t o2 = (size_t)br2 * 1152 + kb + bk2;
            vbh2 = *reinterpret_cast<const short8v*>(Wchi + o2);
            vbl2 = *reinterpret_cast<const short8v*>(Wclo + o2);
        }
    };

    auto STORE = [&]() {
        short8v hv, lv;
#pragma unroll
        for (int q = 0; q < 8; q++) {
            ushort h = f2bf(av[q]);
            hv[q] = (short)h;
            lv[q] = (short)f2bf(av[q] - bf2f(h));
        }
        *reinterpret_cast<short8v*>(&Ahi[rl][kk]) = hv;
        *reinterpret_cast<short8v*>(&Alo[rl][kk]) = lv;
        *reinterpret_cast<short8v*>(&Bhi[br0][bk0]) = vbh0;
        *reinterpret_cast<short8v*>(&Blo[br0][bk0]) = vbl0;
        *reinterpret_cast<short8v*>(&Bhi[br0 + 64][bk0]) = vbh1;
        *reinterpret_cast<short8v*>(&Blo[br0 + 64][bk0]) = vbl1;
        if (tid < 128) {
            *reinterpret_cast<short8v*>(&Bhi[br2][bk2]) = vbh2;
            *reinterpret_cast<short8v*>(&Blo[br2][bk2]) = vbl2;
        }
    };

    f32x4 acc[2][5];
#pragma unroll
    for (int mt = 0; mt < 2; mt++)
#pragma unroll
        for (int nt = 0; nt < 5; nt++) acc[mt][nt] = (f32x4){0.f, 0.f, 0.f, 0.f};

    const int fr = lane & 15, fg = (lane >> 4) << 3;

    LOAD(kbase);
    for (int t = 0; t < NIT; t++) {
        STORE();
        if (t < NIT - 1) LOAD(kbase + (t + 1) * 32);
        __syncthreads();
        short8v ah0 = *reinterpret_cast<const short8v*>(&Ahi[wm * 32 + fr][fg]);
        short8v al0 = *reinterpret_cast<const short8v*>(&Alo[wm * 32 + fr][fg]);
        short8v ah1 = *reinterpret_cast<const short8v*>(&Ahi[wm * 32 + 16 + fr][fg]);
        short8v al1 = *reinterpret_cast<const short8v*>(&Alo[wm * 32 + 16 + fr][fg]);
#pragma unroll
        for (int nt = 0; nt < 5; nt++) {
            short8v bh = *reinterpret_cast<const short8v*>(&Bhi[wn * 80 + nt * 16 + fr][fg]);
            short8v bl = *reinterpret_cast<const short8v*>(&Blo[wn * 80 + nt * 16 + fr][fg]);
            acc[0][nt] = __builtin_amdgcn_mfma_f32_16x16x32_bf16(ah0, bh, acc[0][nt], 0, 0, 0);
            acc[0][nt] = __builtin_amdgcn_mfma_f32_16x16x32_bf16(ah0, bl, acc[0][nt], 0, 0, 0);
            acc[0][nt] = __builtin_amdgcn_mfma_f32_16x16x32_bf16(al0, bh, acc[0][nt], 0, 0, 0);
            acc[1][nt] = __builtin_amdgcn_mfma_f32_16x16x32_bf16(ah1, bh, acc[1][nt], 0, 0, 0);
            acc[1][nt] = __builtin_amdgcn_mfma_f32_16x16x32_bf16(ah1, bl, acc[1][nt], 0, 0, 0);
            acc[1][nt] = __builtin_amdgcn_mfma_f32_16x16x32_bf16(al1, bh, acc[1][nt], 0, 0, 0);
        }
        __syncthreads();
    }

    // epilogue: C/D layout col=lane&15, row=(lane>>4)*4+i  [m89-verified]
    float* base = logits_part + (size_t)ks * RROWS * 160;
#pragma unroll
    for (int mt = 0; mt < 2; mt++) {
#pragma unroll
        for (int nt = 0; nt < 5; nt++) {
            int gcol = wn * 80 + nt * 16 + fr;
            if (gcol < 146) {
                float* dst = base + (size_t)(rb + wm * 32 + mt * 16 + ((lane >> 4) << 2)) * 160 + gcol;
#pragma unroll
                for (int i = 0; i < 4; i++)
                    dst[(size_t)i * 160] = acc[mt][nt][i];
            }
        }
    }
}

// ---------------------------------------------------------------------------
// merged softmax over summed K-slices; DELTA=1 adds rank-40 per-row patch delta.
// ---------------------------------------------------------------------------
template<int DELTA>
__global__ __launch_bounds__(256) void softmax_heads(
    const float* __restrict__ logits_part, const float* __restrict__ cconst,
    float* __restrict__ out_cls, float* __restrict__ out_ext,
    int* __restrict__ amax, float* __restrict__ partials,
    int* __restrict__ cand_count, int* __restrict__ cand_list,
    const float* __restrict__ x, const float* __restrict__ WcT,
    const float* __restrict__ refined5, const int* __restrict__ flag)
{
    __shared__ float ps[4];
    __shared__ float dL[4][148];
    __shared__ float dsh[4][40];
    __shared__ int   ksh[4][40];
    const int r4 = threadIdx.x >> 6, lane = threadIdx.x & 63;
    const int row = blockIdx.x * 4 + r4;

    if (DELTA) {
        const int fl = *flag;
        if (fl) {
            const int b = row / 144, hh = row - b * 144;
            const int a = amax[row];
            if (lane < 40) {
                int c = lane / 5, tw = lane - c * 5;
                int w = a - 2 + tw;
                float d = 0.f; int k = 0;
                if (w >= 0 && w < 144) {
                    k = c * 144 + w;
                    d = refined5[(size_t)b * 5760 + (c * 144 + hh) * 5 + tw]
                      - x[((size_t)(b * 8 + c) * 144 + hh) * 144 + w];
                }
                dsh[r4][lane] = d; ksh[r4][lane] = k;
            }
            __syncthreads();
#pragma unroll
            for (int rj = 0; rj < 3; rj++) {
                int j = lane + rj * 64;
                if (j < 146) {
                    float acc = 0.f;
#pragma unroll 8
                    for (int i = 0; i < 40; i++)
                        acc += WcT[(size_t)ksh[r4][i] * 160 + j] * dsh[r4][i];
                    dL[r4][j] = acc;
                }
            }
        } else {
#pragma unroll
            for (int rj = 0; rj < 3; rj++) {
                int j = lane + rj * 64;
                if (j < 146) dL[r4][j] = 0.f;
            }
        }
        __syncthreads();
    }

    const float* L0 = logits_part + (size_t)row * 160;
    const float* L1 = L0 + (size_t)RROWS * 160;
    float v0 = L0[lane] + L1[lane] + cconst[lane];
    float v1 = L0[lane + 64] + L1[lane + 64] + cconst[lane + 64];
    float v2 = (lane < 16) ? (L0[lane + 128] + L1[lane + 128] + cconst[lane + 128])
                           : -3.0e38f;
    if (DELTA) {
        v0 += dL[r4][lane];
        v1 += dL[r4][lane + 64];
        if (lane < 16) v2 += dL[r4][lane + 128];
    }
    float m = v0; int mi = lane;
    if (v1 > m) { m = v1; mi = lane + 64; }
    if (v2 > m) { m = v2; mi = lane + 128; }
    float m1 = v0, m2 = -3.0e38f;
    if (v1 > m1) { m2 = m1; m1 = v1; } else m2 = v1;
    if (v2 > m1) { m2 = m1; m1 = v2; } else m2 = fmaxf(m2, v2);
#pragma unroll
    for (int off = 32; off; off >>= 1) {
        float om = __shfl_xor(m, off);
        int   oi = __shfl_xor(mi, off);
        if (om > m || (om == m && oi < mi)) { m = om; mi = oi; }
        float om1 = __shfl_xor(m1, off);
        float om2 = __shfl_xor(m2, off);
        float nm1 = fmaxf(m1, om1);
        m2 = fmaxf(fminf(m1, om1), fmaxf(m2, om2));
        m1 = nm1;
    }
    float e0 = expf(v0 - m), e1 = expf(v1 - m);
    float e2 = (lane < 16) ? expf(v2 - m) : 0.f;
    float s = e0 + e1 + e2;
#pragma unroll
    for (int off = 32; off; off >>= 1) s += __shfl_xor(s, off);
    float inv = 1.f / s;
    float* O = out_cls + (size_t)row * 144;
    O[lane] = e0 * inv;
    O[lane + 64] = e1 * inv;
    if (lane < 16) O[lane + 128] = e2 * inv;

    float l0 = L0[144] + L1[144] + cconst[144];
    float l1 = L0[145] + L1[145] + cconst[145];
    if (DELTA) { l0 += dL[r4][144]; l1 += dL[r4][145]; }
    float mx = fmaxf(l0, l1);
    float ee0 = expf(l0 - mx), ee1 = expf(l1 - mx);
    float einv = 1.f / (ee0 + ee1);
    float p0 = ee0 * einv;
    if (lane == 0) {
        out_ext[(size_t)row * 2] = p0;
        out_ext[(size_t)row * 2 + 1] = ee1 * einv;
        if (amax != nullptr && !DELTA) {
            amax[row] = mi;
            if (m1 - m2 < GAPTH) {
                int slot = atomicAdd(cand_count, 1);
                cand_list[slot] = row;
            }
        }
    }
    if (partials != nullptr) {
        if (lane == 0) ps[r4] = p0;
        __syncthreads();
        if (threadIdx.x == 0) partials[blockIdx.x] = (ps[0] + ps[1]) + (ps[2] + ps[3]);
    }
}

__global__ __launch_bounds__(256) void reduce_flag(const float* __restrict__ partials, int n,
                                                   int* __restrict__ flag)
{
    __shared__ float sm[256];
    int tid = threadIdx.x;
    float s = 0.f;
    for (int i = tid; i < n; i += 256) s += partials[i];
    sm[tid] = s; __syncthreads();
    for (int off = 128; off; off >>= 1) {
        if (tid < off) sm[tid] += sm[tid + off];
        __syncthreads();
    }
    if (tid == 0) *flag = (sm[0] * (1.f / 18432.f) > 0.3f) ? 1 : 0;
}

// ---------------------------------------------------------------------------
// fixup over compacted candidate list: exact f32 two-stage recompute of argmax.
// 4-accumulator ILP in both stages (break dependent FMA chain).
// ---------------------------------------------------------------------------
__global__ __launch_bounds__(256) void fixup_list(
    const int* __restrict__ cand_count, const int* __restrict__ cand_list,
    const float* __restrict__ x,
    const float* __restrict__ w1cT, const float* __restrict__ b1c,
    const float* __restrict__ gc, const float* __restrict__ bbc,
    const float* __restrict__ mc, const float* __restrict__ vc,
    const float* __restrict__ w2cT, const float* __restrict__ b2c,
    int* __restrict__ amax)
{
    __shared__ float xrow[1152];
    __shared__ float hsh[256];
    __shared__ float Lsh[144];
    const int tid = threadIdx.x;
    const int n = *cand_count;

    for (int ci = blockIdx.x; ci < n; ci += gridDim.x) {
        const int row = cand_list[ci];
        const int b = row / 144, hh = row - b * 144;
        for (int e = tid; e < 1152; e += 256) {
            int c = e / 144, w = e - c * 144;
            xrow[e] = x[(((size_t)(b * 8 + c) * 144 + hh) * 144) + w];
        }
        __syncthreads();
        {
            float a0 = 0.f, a1 = 0.f, a2 = 0.f, a3 = 0.f;
#pragma unroll 4
            for (int k = 0; k < 1152; k += 4) {
                a0 += w1cT[(size_t)k * 256 + tid] * xrow[k];
                a1 += w1cT[(size_t)(k + 1) * 256 + tid] * xrow[k + 1];
                a2 += w1cT[(size_t)(k + 2) * 256 + tid] * xrow[k + 2];
                a3 += w1cT[(size_t)(k + 3) * 256 + tid] * xrow[k + 3];
            }
            float a = (a0 + a1) + (a2 + a3);
            float sc = gc[tid] * rsqrtf(vc[tid] + EPSF);
            hsh[tid] = (a + b1c[tid] - mc[tid]) * sc + bbc[tid];
        }
        __syncthreads();
        if (tid < 144) {
            float a0 = 0.f, a1 = 0.f, a2 = 0.f, a3 = 0.f;
#pragma unroll 4
            for (int k = 0; k < 256; k += 4) {
                a0 += w2cT[(size_t)k * 144 + tid] * hsh[k];
                a1 += w2cT[(size_t)(k + 1) * 144 + tid] * hsh[k + 1];
                a2 += w2cT[(size_t)(k + 2) * 144 + tid] * hsh[k + 2];
                a3 += w2cT[(size_t)(k + 3) * 144 + tid] * hsh[k + 3];
            }
            Lsh[tid] = (a0 + a1) + (a2 + a3) + b2c[tid];
        }
        __syncthreads();
        if (tid == 0) {
            int bi = 0; float bv = Lsh[0];
            for (int j = 1; j < 144; j++) if (Lsh[j] > bv) { bv = Lsh[j]; bi = j; }
            amax[row] = bi;
        }
        __syncthreads();
    }
}

// ---------------------------------------------------------------------------
// tok GEMM with fused patch gather; 4 accumulators for ILP.
// ---------------------------------------------------------------------------
__global__ __launch_bounds__(256) void tok_partial(const float* __restrict__ x,
    const int* __restrict__ amax, const float* __restrict__ tok_w, float* __restrict__ tpart)
{
    __shared__ float P[720];
    __shared__ int ash[144];
    int b = blockIdx.x, c = blockIdx.y, tid = threadIdx.x;
    if (tid < 144) ash[tid] = amax[b * 144 + tid];
    __syncthreads();
    for (int e = tid; e < 720; e += 256) {
        int hh = e / 5, tw = e - hh * 5;
        int w = ash[hh] + tw - 2;
        P[e] = (w >= 0 && w < 144) ? x[(((size_t)(b * 8 + c) * 144 + hh) * 144) + w] : 0.f;
    }
    __syncthreads();
    const float* wbase = tok_w + (size_t)c * 720 * 256;
    float a0 = 0.f, a1 = 0.f, a2 = 0.f, a3 = 0.f;
    for (int k = 0; k < 720; k += 4) {
        a0 += P[k]     * wbase[(size_t)k * 256 + tid];
        a1 += P[k + 1] * wbase[(size_t)(k + 1) * 256 + tid];
        a2 += P[k + 2] * wbase[(size_t)(k + 2) * 256 + tid];
        a3 += P[k + 3] * wbase[(size_t)(k + 3) * 256 + tid];
    }
    tpart[((size_t)b * 8 + c) * 256 + tid] = (a0 + a1) + (a2 + a3);
}

// ---------------------------------------------------------------------------
// attn_front: tok_finish + LN1(x6) + qkv (q only token 5) + attention row 5
// + out-proj token 5 + residual + LN2.  512 threads; 4-lane k-split dots.
// ---------------------------------------------------------------------------
__global__ __launch_bounds__(512) void attn_front(
    const float* __restrict__ tpart, const float* __restrict__ tok_b,
    const float* __restrict__ emb,
    const float* __restrict__ ln1_g, const float* __restrict__ ln1_b,
    const float* __restrict__ qkv_w,
    const float* __restrict__ out_w, const float* __restrict__ out_b,
    const float* __restrict__ ln2_g, const float* __restrict__ ln2_b,
    float* __restrict__ z2_5, float* __restrict__ t5out)
{
    __shared__ float s[256];
    __shared__ float z[6][256];
    __shared__ float qk[6][192];
    __shared__ float att[2][6];
    __shared__ float o5[64];
    __shared__ float t5[256];
    __shared__ float stat[2];
    const int b = blockIdx.x, tid = threadIdx.x;
    const int lane = tid & 63, wv = tid >> 6;
    const int g4 = tid >> 2, l4 = tid & 3;

    if (tid < 256) {
        float a = tok_b[tid];
#pragma unroll
        for (int ks = 0; ks < 8; ks++) a += tpart[((size_t)b * 8 + ks) * 256 + tid];
        s[tid] = a;
    }
    __syncthreads();

    if (wv < 6) {
        float y[4], s1 = 0.f, s2 = 0.f;
#pragma unroll
        for (int q = 0; q < 4; q++) {
            int k = lane + 64 * q;
            y[q] = s[k] + emb[wv * 256 + k];
            s1 += y[q]; s2 += y[q] * y[q];
        }
#pragma unroll
        for (int off = 32; off; off >>= 1) { s1 += __shfl_xor(s1, off); s2 += __shfl_xor(s2, off); }
        float mu = s1 * (1.f / 256.f);
        float var = s2 * (1.f / 256.f) - mu * mu;
        float rs = rsqrtf(var + EPSF);
#pragma unroll
        for (int q = 0; q < 4; q++) {
            int k = lane + 64 * q;
            z[wv][k] = (y[q] - mu) * rs * ln1_g[k] + ln1_b[k];
        }
    }
    __syncthreads();

    for (int tt = g4; tt < 832; tt += 128) {
        int i, c;
        if (tt < 768) { i = tt >> 7; c = 64 + (tt & 127); }
        else          { i = 5;       c = tt - 768; }
        float a = 0.f;
#pragma unroll 8
        for (int j = 0; j < 64; j++) {
            int k = l4 + 4 * j;
            a += z[i][k] * qkv_w[(size_t)k * 192 + c];
        }
        a += __shfl_xor(a, 1);
        a += __shfl_xor(a, 2);
        if (l4 == 0) qk[i][c] = a;
    }
    __syncthreads();

    if (tid < 12) {
        int h = tid / 6, j = tid - h * 6;
        float a = 0.f;
#pragma unroll
        for (int d = 0; d < 32; d++) a += qk[5][h * 32 + d] * qk[j][64 + h * 32 + d];
        att[h][j] = a * 0.17677669529663687f;
    }
    __syncthreads();
    if (tid < 2) {
        float m = -3.0e38f;
        for (int j = 0; j < 6; j++) m = fmaxf(m, att[tid][j]);
        float ssum = 0.f;
        for (int j = 0; j < 6; j++) { float e = expf(att[tid][j] - m); att[tid][j] = e; ssum += e; }
        float inv = 1.f / ssum;
        for (int j = 0; j < 6; j++) att[tid][j] *= inv;
    }
    __syncthreads();
    if (tid < 64) {
        int h = tid >> 5;
        float a = 0.f;
#pragma unroll
        for (int j = 0; j < 6; j++) a += att[h][j] * qk[j][128 + tid];
        o5[tid] = a;
    }
    __syncthreads();

    for (int tt = g4; tt < 256; tt += 128) {
        float a = 0.f;
#pragma unroll
        for (int j = 0; j < 16; j++) {
            int d = l4 + 4 * j;
            a += o5[d] * out_w[(size_t)d * 256 + tt];
        }
        a += __shfl_xor(a, 1);
        a += __shfl_xor(a, 2);
        if (l4 == 0) t5[tt] = a + out_b[tt] + s[tt] + emb[5 * 256 + tt];
    }
    __syncthreads();

    if (wv == 0) {
        float s1 = 0.f, s2 = 0.f;
#pragma unroll
        for (int q = 0; q < 4; q++) { float vv = t5[lane + 64 * q]; s1 += vv; s2 += vv * vv; }
#pragma unroll
        for (int off = 32; off; off >>= 1) { s1 += __shfl_xor(s1, off); s2 += __shfl_xor(s2, off); }
        if (lane == 0) {
            float mu = s1 * (1.f / 256.f);
            float var = s2 * (1.f / 256.f) - mu * mu;
            stat[0] = mu; stat[1] = rsqrtf(var + EPSF);
        }
    }
    __syncthreads();
    if (tid < 256) {
        t5out[(size_t)b * 256 + tid] = t5[tid];
        z2_5[(size_t)b * 256 + tid] = (t5[tid] - stat[0]) * stat[1] * ln2_g[tid] + ln2_b[tid];
    }
}

// ---------------------------------------------------------------------------
// ff1 + exact gelu for token 5: 4-lane k-split, 512 threads
// ---------------------------------------------------------------------------
__global__ __launch_bounds__(512) void ff1_gelu(
    const float* __restrict__ z2_5, const float* __restrict__ ff_w1,
    const float* __restrict__ ff_b1, float* __restrict__ f5)
{
    __shared__ float zsh[256];
    const int b = blockIdx.x, half = blockIdx.y, tid = threadIdx.x;
    const int g4 = tid >> 2, l4 = tid & 3;
    if (tid < 256) zsh[tid] = z2_5[(size_t)b * 256 + tid];
    __syncthreads();
    for (int tt = g4; tt < 256; tt += 128) {
        const int jj = half * 256 + tt;
        float a = 0.f;
#pragma unroll 8
        for (int j = 0; j < 64; j++) {
            int k = l4 + 4 * j;
            a += zsh[k] * ff_w1[(size_t)k * 512 + jj];
        }
        a += __shfl_xor(a, 1);
        a += __shfl_xor(a, 2);
        if (l4 == 0) {
            a += ff_b1[jj];
            f5[(size_t)b * 512 + jj] = 0.5f * a * (1.f + erff(a * 0.70710678118654752f));
        }
    }
}

// ---------------------------------------------------------------------------
// ff2 + residual + LNF for token 5 -> tfin: 4-lane k-split, 512 threads
// ---------------------------------------------------------------------------
__global__ __launch_bounds__(512) void ff2_lnf(
    const float* __restrict__ f5, const float* __restrict__ ff_w2,
    const float* __restrict__ ff_b2, const float* __restrict__ t5in,
    const float* __restrict__ lnf_g, const float* __restrict__ lnf_b,
    float* __restrict__ tfin)
{
    __shared__ float fsh[512];
    __shared__ float tsh[256];
    __shared__ float stat[2];
    const int b = blockIdx.x, tid = threadIdx.x;
    const int lane = tid & 63, wv = tid >> 6;
    const int g4 = tid >> 2, l4 = tid & 3;
    fsh[tid] = f5[(size_t)b * 512 + tid];
    __syncthreads();
    for (int tt = g4; tt < 256; tt += 128) {
        float a = 0.f;
#pragma unroll 8
        for (int j = 0; j < 128; j++) {
            int k = l4 + 4 * j;
            a += fsh[k] * ff_w2[(size_t)k * 256 + tt];
        }
        a += __shfl_xor(a, 1);
        a += __shfl_xor(a, 2);
        if (l4 == 0) tsh[tt] = a + ff_b2[tt] + t5in[(size_t)b * 256 + tt];
    }
    __syncthreads();
    if (wv == 0) {
        float s1 = 0.f, s2 = 0.f;
#pragma unroll
        for (int q = 0; q < 4; q++) { float vv = tsh[lane + 64 * q]; s1 += vv; s2 += vv * vv; }
#pragma unroll
        for (int off = 32; off; off >>= 1) { s1 += __shfl_xor(s1, off); s2 += __shfl_xor(s2, off); }
        if (lane == 0) {
            float mu = s1 * (1.f / 256.f);
            float var = s2 * (1.f / 256.f) - mu * mu;
            stat[0] = mu; stat[1] = rsqrtf(var + EPSF);
        }
    }
    __syncthreads();
    if (tid < 256)
        tfin[(size_t)b * 256 + tid] = (tsh[tid] - stat[0]) * stat[1] * lnf_g[tid] + lnf_b[tid];
}

// ---------------------------------------------------------------------------
// fin GEMM for token 5: refined5[b,n] = tfin[b,:] @ fin_w[:,n] + fin_b[n]
// ---------------------------------------------------------------------------
__global__ __launch_bounds__(256) void fin_gemm(const float* __restrict__ tfin,
    const float* __restrict__ fin_w, const float* __restrict__ fin_b, float* __restrict__ refined5)
{
    __shared__ float tf[16][256];
    int tid = threadIdx.x;
    int nb = blockIdx.x * 256 + tid;
    int bg = blockIdx.y * 16;
    for (int e = tid; e < 4096; e += 256) tf[e >> 8][e & 255] = tfin[(size_t)(bg + (e >> 8)) * 256 + (e & 255)];
    __syncthreads();
    if (nb < 5760) {
        float acc[16];
#pragma unroll
        for (int bb = 0; bb < 16; bb++) acc[bb] = 0.f;
        for (int k = 0; k < 256; k++) {
            float wv = fin_w[(size_t)k * 5760 + nb];
#pragma unroll
            for (int bb = 0; bb < 16; bb++) acc[bb] += tf[bb][k] * wv;
        }
        float fb = fin_b[nb];
#pragma unroll
        for (int bb = 0; bb < 16; bb++)
            refined5[(size_t)(bg + bb) * 5760 + nb] = acc[bb] + fb;
    }
}

// ---------------------------------------------------------------------------
extern "C" void kernel_launch(void* const* d_in, const int* in_sizes, int n_in,
                              void* d_out, int out_size, void* d_ws, size_t ws_size,
                              hipStream_t stream)
{
    const float* x      = (const float*)d_in[0];
    const float* ext_w1 = (const float*)d_in[1];
    const float* ext_b1 = (const float*)d_in[2];
    const float* ext_g  = (const float*)d_in[3];
    const float* ext_bb = (const float*)d_in[4];
    const float* ext_m  = (const float*)d_in[5];
    const float* ext_v  = (const float*)d_in[6];
    const float* ext_w2 = (const float*)d_in[7];
    const float* ext_b2 = (const float*)d_in[8];
    const float* cls_w1 = (const float*)d_in[9];
    const float* cls_b1 = (const float*)d_in[10];
    const float* cls_g  = (const float*)d_in[11];
    const float* cls_bb = (const float*)d_in[12];
    const float* cls_m  = (const float*)d_in[13];
    const float* cls_v  = (const float*)d_in[14];
    const float* cls_w2 = (const float*)d_in[15];
    const float* cls_b2 = (const float*)d_in[16];
    const float* tok_w  = (const float*)d_in[17];
    const float* tok_b  = (const float*)d_in[18];
    const float* emb    = (const float*)d_in[19];
    const float* ln1_g  = (const float*)d_in[20];
    const float* ln1_b  = (const float*)d_in[21];
    const float* qkv_w  = (const float*)d_in[22];
    const float* out_w  = (const float*)d_in[23];
    const float* out_b  = (const float*)d_in[24];
    const float* ln2_g  = (const float*)d_in[25];
    const float* ln2_b  = (const float*)d_in[26];
    const float* ff_w1  = (const float*)d_in[27];
    const float* ff_b1  = (const float*)d_in[28];
    const float* ff_w2  = (const float*)d_in[29];
    const float* ff_b2  = (const float*)d_in[30];
    const float* lnf_g  = (const float*)d_in[31];
    const float* lnf_b  = (const float*)d_in[32];
    const float* fin_w  = (const float*)d_in[33];
    const float* fin_b  = (const float*)d_in[34];

    float* out = (float*)d_out;
    float* ws  = (float*)d_ws;

    // workspace layout (float offsets)
    float*  Wc32     = ws;                        // 184320
    float*  cconst   = ws + 184320;               // 160
    ushort* Wchi     = (ushort*)(ws + 184480);    // 92160 floats
    ushort* Wclo     = (ushort*)(ws + 276640);    // 92160 floats
    float*  logitsP  = ws + 368800;               // 2*18432*160 = 5898240
    float*  partials = ws + 6267040;              // 4608
    float*  z2_5     = ws + 6271648;              // 32768
    float*  t5buf    = ws + 6304416;              // 32768
    float*  f5buf    = ws + 6337184;              // 65536
    float*  tfin     = ws + 6402720;              // 32768
    float*  refined5 = ws + 6435488;              // 737280
    float*  tpart    = ws + 7172768;              // 262144
    int*    amax     = (int*)(ws + 7434912);      // 18432
    int*    flag     = (int*)(ws + 7453344);      // 1
    int*    cand_cnt = (int*)(ws + 7453345);      // 1
    int*    cand_lst = (int*)(ws + 7453346);      // 18432
    float*  w1cT     = ws + 7471780;              // 294912
    float*  w2cT     = ws + 7766692;              // 36864
    float*  WcT      = ws + 7803556;              // 184320 -> ends 7987876

    // output offsets: ext | cls | ext2 | cls2
    float* out_ext  = out;
    float* out_cls  = out + 36864;
    float* out_ext2 = out + 2691072;
    float* out_cls2 = out + 2727936;

    dim3 blk(256);

    // weight prep (independent of x)
    wcomb_build<<<dim3(160, 4), blk, 0, stream>>>(
        ext_w1, ext_b1, ext_g, ext_bb, ext_m, ext_v, ext_w2, ext_b2,
        cls_w1, cls_b1, cls_g, cls_bb, cls_m, cls_v, cls_w2, cls_b2,
        Wc32, Wchi, Wclo, cconst);
    zero_counters<<<1, 1, 0, stream>>>(cand_cnt);
    transpose_w<<<dim3(36, 8), blk, 0, stream>>>(cls_w1, w1cT, 256, 1152);
    transpose_w<<<dim3(8, 5), blk, 0, stream>>>(cls_w2, w2cT, 144, 256);
    transpose_w<<<dim3(36, 5), blk, 0, stream>>>(Wc32, WcT, 160, 1152);

    // pass 1
    logits_gemm<<<dim3(288, NKS), blk, 0, stream>>>(x, Wchi, Wclo, logitsP);
    softmax_heads<0><<<4608, blk, 0, stream>>>(logitsP, cconst, out_cls, out_ext, amax, partials,
        cand_cnt, cand_lst, nullptr, nullptr, nullptr, nullptr);
    reduce_flag<<<1, blk, 0, stream>>>(partials, 4608, flag);
    fixup_list<<<256, blk, 0, stream>>>(cand_cnt, cand_lst, x,
        w1cT, cls_b1, cls_g, cls_bb, cls_m, cls_v, w2cT, cls_b2, amax);

    // refine chain (always computed; application predicated on flag)
    tok_partial<<<dim3(128, 8), blk, 0, stream>>>(x, amax, tok_w, tpart);
    attn_front<<<128, dim3(512), 0, stream>>>(tpart, tok_b, emb, ln1_g, ln1_b, qkv_w,
        out_w, out_b, ln2_g, ln2_b, z2_5, t5buf);
    ff1_gelu<<<dim3(128, 2), dim3(512), 0, stream>>>(z2_5, ff_w1, ff_b1, f5buf);
    ff2_lnf<<<128, dim3(512), 0, stream>>>(f5buf, ff_w2, ff_b2, t5buf, lnf_g, lnf_b, tfin);
    fin_gemm<<<dim3(23, 8), blk, 0, stream>>>(tfin, fin_w, fin_b, refined5);

    // pass 2 = pass 1 logits + rank-40 delta fused into softmax
    softmax_heads<1><<<4608, blk, 0, stream>>>(logitsP, cconst, out_cls2, out_ext2, amax, nullptr,
        nullptr, nullptr, x, WcT, refined5, flag);
}